// Round 6
// baseline (179.711 us; speedup 1.0000x reference)
//
#include <hip/hip_runtime.h>
#include <math.h>

#define BB 32
#define NN 64
#define PP 4
#define HH 300

#define NKK 10    // edge reduction tiles: ceil(300/32)
#define NCT 19    // output col-tiles of 16: ceil(300/16)
#define NKK2 38   // node reduction tiles: ceil(1200/32)
#define CHK 10    // node kk chunk size (4 chunks cover 38)

typedef float f32x4  __attribute__((ext_vector_type(4)));
typedef short bf16x8 __attribute__((ext_vector_type(8)));

__device__ __forceinline__ float eluf(float x) {
    return x > 0.0f ? x : (__expf(x) - 1.0f);
}

// round-to-nearest-even fp32 -> bf16 bits
__device__ __forceinline__ unsigned short f2bf(float x) {
    unsigned u = __float_as_uint(x);
    u += 0x7FFFu + ((u >> 16) & 1u);
    return (unsigned short)(u >> 16);
}
__device__ __forceinline__ float bf2f(unsigned short s) {
    return __uint_as_float(((unsigned)s) << 16);
}

// ---------------------------------------------------------------------------
// Pre-convert W_edge (300x300 fp32) into MFMA B-fragment-linear bf16 (hi only;
// 2-pass split keeps A fp32-grade, B rounded to bf16):
// tile (kk, ct): lane l, elem j holds W[h][k], h = kk*32 + (l>>4)*8 + j,
// k = ct*16 + (l&15); zero-padded outside 300.
// ---------------------------------------------------------------------------
extern "C" __global__ __launch_bounds__(64)
void wprep_kernel(const float* __restrict__ w_edge,
                  short* __restrict__ w_hi)
{
    const int tile = (int)blockIdx.x;          // kk*NCT + ct
    const int kk = tile / NCT, ct = tile % NCT;
    const int lane = (int)threadIdx.x;
    const int h0 = kk * 32 + (lane >> 4) * 8;
    const int k  = ct * 16 + (lane & 15);
    const size_t base = ((size_t)tile * 64 + lane) * 8;
#pragma unroll
    for (int j = 0; j < 8; ++j) {
        int h = h0 + j;
        float v = (h < HH && k < HH) ? w_edge[h * HH + k] : 0.f;
        w_hi[base + j] = (short)f2bf(v);
    }
}

// Same for W_np flattened to 1200x300 (K index = p*300+h).
extern "C" __global__ __launch_bounds__(64)
void wprep2_kernel(const float* __restrict__ w_np,
                   short* __restrict__ w2_hi)
{
    const int tile = (int)blockIdx.x;          // kk*NCT + ct
    const int kk = tile / NCT, ct = tile % NCT;
    const int lane = (int)threadIdx.x;
    const int h0 = kk * 32 + (lane >> 4) * 8;
    const int k  = ct * 16 + (lane & 15);
    const size_t base = ((size_t)tile * 64 + lane) * 8;
#pragma unroll
    for (int j = 0; j < 8; ++j) {
        int h = h0 + j;
        float v = (h < PP * HH && k < HH) ? w_np[(size_t)h * HH + k] : 0.f;
        w2_hi[base + j] = (short)f2bf(v);
    }
}

// ---------------------------------------------------------------------------
// Edge path via MFMA, 2-pass bf16 split (A fp32-grade, B bf16).
// One block per (b, m-PAIR): grid B*N/2. Each wave owns n-rows
// [16wv,16wv+16) of BOTH m0 and m1 -> every B LDS read feeds 4 MFMAs
// (2 m x hi/lo passes, 4 independent accumulator chains for ILP), and
// per-CU B-LDS traffic halves vs the 1-m version.
// B-fragments LDS-staged per col-tile, double-buffered (reg-staged:
// issue loads(ct+1) early -> compute(ct) -> ds_write -> barrier).
// NOTE: no min-waves force in launch_bounds (round-4 lesson: (256,4)
// capped VGPR at 64 and spilled A-fragments -> 180 MB scratch writes).
// ---------------------------------------------------------------------------
extern "C" __global__ __launch_bounds__(256)
void edge_kernel(const float* __restrict__ edge_attr,
                 const float* __restrict__ instr,
                 const float* __restrict__ dist,
                 const float* __restrict__ node_mask,
                 const short* __restrict__ w_hi,
                 const float* __restrict__ w_rel,
                 float* __restrict__ rel_logits)
{
    __shared__ short Bs[2][NKK * 512];   // 2 x 10 KB, tile kk at [kk*512]
    __shared__ float red[2][NN];
    const int b    = (int)blockIdx.x / (NN / 2);
    const int mp   = (int)blockIdx.x % (NN / 2);
    const int m0   = 2 * mp;
    const int tid  = (int)threadIdx.x;
    const int wv   = tid >> 6;
    const int lane = tid & 63;
    const int lrow = lane & 15;
    const int lgrp = lane >> 4;

    // ---- A fragments (hi/lo) for both m's, read-once from global ----
    bf16x8 a_hi[2][NKK], a_lo[2][NKK];
#pragma unroll
    for (int mi = 0; mi < 2; ++mi) {
        const float* arow = edge_attr
            + (size_t)((b * NN + m0 + mi) * NN + wv * 16 + lrow) * HH;
#pragma unroll
        for (int kk = 0; kk < NKK; ++kk) {
            const int h0 = kk * 32 + lgrp * 8;
            float v[8];
            if (h0 + 7 < HH) {
                f32x4 p0 = *reinterpret_cast<const f32x4*>(arow + h0);
                f32x4 p1 = *reinterpret_cast<const f32x4*>(arow + h0 + 4);
                v[0] = p0[0]; v[1] = p0[1]; v[2] = p0[2]; v[3] = p0[3];
                v[4] = p1[0]; v[5] = p1[1]; v[6] = p1[2]; v[7] = p1[3];
            } else {
#pragma unroll
                for (int j = 0; j < 8; ++j)
                    v[j] = (h0 + j < HH) ? arow[h0 + j] : 0.f;
            }
#pragma unroll
            for (int j = 0; j < 8; ++j) {
                unsigned short hb = f2bf(v[j]);
                a_hi[mi][kk][j] = (short)hb;
                a_lo[mi][kk][j] = (short)f2bf(v[j] - bf2f(hb));
            }
        }
    }

    const bf16x8* WH = reinterpret_cast<const bf16x8*>(w_hi);
    const int binst = b * HH;

    // staging: wave wv owns tiles kk = wv, wv+4, wv+8
    bf16x8 st[3];

    // prologue: stage ct=0 into buf 0
#pragma unroll
    for (int i = 0; i < 3; ++i) {
        const int kk = wv + 4 * i;
        if (kk < NKK) st[i] = WH[(kk * NCT + 0) * 64 + lane];
    }
#pragma unroll
    for (int i = 0; i < 3; ++i) {
        const int kk = wv + 4 * i;
        if (kk < NKK)
            *reinterpret_cast<bf16x8*>(&Bs[0][kk * 512 + lane * 8]) = st[i];
    }
    __syncthreads();

    float rs00 = 0.f, rs01 = 0.f, rs02 = 0.f, rs03 = 0.f;   // m0 rows
    float rs10 = 0.f, rs11 = 0.f, rs12 = 0.f, rs13 = 0.f;   // m1 rows
    int cur = 0;

#pragma unroll 1
    for (int ct = 0; ct < NCT; ++ct) {
        // issue next tile's loads early
        if (ct + 1 < NCT) {
#pragma unroll
            for (int i = 0; i < 3; ++i) {
                const int kk = wv + 4 * i;
                if (kk < NKK) st[i] = WH[(kk * NCT + ct + 1) * 64 + lane];
            }
        }

        // compute current tile from LDS: 4 independent accumulator chains
        f32x4 aH0 = {0.f, 0.f, 0.f, 0.f};
        f32x4 aL0 = {0.f, 0.f, 0.f, 0.f};
        f32x4 aH1 = {0.f, 0.f, 0.f, 0.f};
        f32x4 aL1 = {0.f, 0.f, 0.f, 0.f};
#pragma unroll
        for (int kk = 0; kk < NKK; ++kk) {
            bf16x8 bh = *reinterpret_cast<const bf16x8*>(
                &Bs[cur][kk * 512 + lane * 8]);
            aH0 = __builtin_amdgcn_mfma_f32_16x16x32_bf16(a_hi[0][kk], bh, aH0, 0, 0, 0);
            aL0 = __builtin_amdgcn_mfma_f32_16x16x32_bf16(a_lo[0][kk], bh, aL0, 0, 0, 0);
            aH1 = __builtin_amdgcn_mfma_f32_16x16x32_bf16(a_hi[1][kk], bh, aH1, 0, 0, 0);
            aL1 = __builtin_amdgcn_mfma_f32_16x16x32_bf16(a_lo[1][kk], bh, aL1, 0, 0, 0);
        }

        // fused epilogue: col k = ct*16 + lrow, rows = lgrp*4 + i
        const int k  = ct * 16 + lrow;
        const bool ok = k < HH;
        const int kc = ok ? k : (HH - 1);
        const float iv = instr[binst + kc];
        const float wr = ok ? w_rel[kc] : 0.f;
        rs00 += eluf((aH0[0] + aL0[0]) * iv) * wr;
        rs01 += eluf((aH0[1] + aL0[1]) * iv) * wr;
        rs02 += eluf((aH0[2] + aL0[2]) * iv) * wr;
        rs03 += eluf((aH0[3] + aL0[3]) * iv) * wr;
        rs10 += eluf((aH1[0] + aL1[0]) * iv) * wr;
        rs11 += eluf((aH1[1] + aL1[1]) * iv) * wr;
        rs12 += eluf((aH1[2] + aL1[2]) * iv) * wr;
        rs13 += eluf((aH1[3] + aL1[3]) * iv) * wr;

        // write next tile into the other buffer
        if (ct + 1 < NCT) {
#pragma unroll
            for (int i = 0; i < 3; ++i) {
                const int kk = wv + 4 * i;
                if (kk < NKK)
                    *reinterpret_cast<bf16x8*>(
                        &Bs[cur ^ 1][kk * 512 + lane * 8]) = st[i];
            }
            __syncthreads();
        }
        cur ^= 1;
    }

    // reduce over the 16 lanes sharing the same C-rows (masks 1,2,4,8)
#pragma unroll
    for (int msk = 1; msk < 16; msk <<= 1) {
        rs00 += __shfl_xor(rs00, msk);
        rs01 += __shfl_xor(rs01, msk);
        rs02 += __shfl_xor(rs02, msk);
        rs03 += __shfl_xor(rs03, msk);
        rs10 += __shfl_xor(rs10, msk);
        rs11 += __shfl_xor(rs11, msk);
        rs12 += __shfl_xor(rs12, msk);
        rs13 += __shfl_xor(rs13, msk);
    }
    if (lrow == 0) {
        const int r0 = wv * 16 + lgrp * 4;
        red[0][r0 + 0] = rs00;
        red[0][r0 + 1] = rs01;
        red[0][r0 + 2] = rs02;
        red[0][r0 + 3] = rs03;
        red[1][r0 + 0] = rs10;
        red[1][r0 + 1] = rs11;
        red[1][r0 + 2] = rs12;
        red[1][r0 + 3] = rs13;
    }
    __syncthreads();
    if (tid < 128) {
        const int mi = tid >> 6;      // wave 0 -> m0, wave 1 -> m1
        const int ln = tid & 63;
        float v = red[mi][ln] * dist[b * NN + ln];
#pragma unroll
        for (int msk = 1; msk < 64; msk <<= 1) v += __shfl_xor(v, msk);
        if (ln == 0)
            rel_logits[b * NN + m0 + mi] = v + node_mask[b * NN + m0 + mi];
    }
}

// ---------------------------------------------------------------------------
// Node path via MFMA (2-pass): A[b,n,K=1200] (sim folded) @ Wflat[1200x300].
// One block per (b, 16-row n-tile); 4 waves split the 19 col-tiles.
// ---------------------------------------------------------------------------
extern "C" __global__ __launch_bounds__(256)
void node_mfma_kernel(const float* __restrict__ node_attr,
                      const float* __restrict__ instr,
                      const float* __restrict__ sim,
                      const float* __restrict__ node_mask,
                      const short* __restrict__ w2_hi,
                      const float* __restrict__ w_state,
                      float* __restrict__ state_logits)
{
    __shared__ float red[4][16];
    const int b    = (int)blockIdx.x >> 2;
    const int nt   = (int)blockIdx.x & 3;
    const int tid  = (int)threadIdx.x;
    const int wv   = tid >> 6;
    const int lane = tid & 63;
    const int lrow = lane & 15;
    const int lgrp = lane >> 4;

    const float* arow = node_attr
        + (size_t)(b * NN + nt * 16 + lrow) * (PP * HH);
    float sm[PP];
#pragma unroll
    for (int p = 0; p < PP; ++p) sm[p] = sim[b * PP + p];

    const bf16x8* WH = reinterpret_cast<const bf16x8*>(w2_hi);

    f32x4 acc[5] = {{0.f,0.f,0.f,0.f},{0.f,0.f,0.f,0.f},{0.f,0.f,0.f,0.f},
                    {0.f,0.f,0.f,0.f},{0.f,0.f,0.f,0.f}};

#pragma unroll 1
    for (int ch = 0; ch < 4; ++ch) {
        bf16x8 a_hi[CHK], a_lo[CHK];
#pragma unroll
        for (int q = 0; q < CHK; ++q) {
            const int kk = ch * CHK + q;
            const int h0 = kk * 32 + lgrp * 8;
            float v[8];
            if (kk < NKK2 && h0 + 7 < PP * HH) {
                f32x4 p0 = *reinterpret_cast<const f32x4*>(arow + h0);
                f32x4 p1 = *reinterpret_cast<const f32x4*>(arow + h0 + 4);
                v[0] = p0[0]; v[1] = p0[1]; v[2] = p0[2]; v[3] = p0[3];
                v[4] = p1[0]; v[5] = p1[1]; v[6] = p1[2]; v[7] = p1[3];
            } else {
#pragma unroll
                for (int j = 0; j < 8; ++j)
                    v[j] = (kk < NKK2 && h0 + j < PP * HH) ? arow[h0 + j] : 0.f;
            }
#pragma unroll
            for (int j = 0; j < 8; ++j) {
                const int h = h0 + j;
                const int p = (h < PP * HH) ? (h / HH) : 0;
                float x = v[j] * sm[p];
                unsigned short hb = f2bf(x);
                a_hi[q][j] = (short)hb;
                a_lo[q][j] = (short)f2bf(x - bf2f(hb));
            }
        }
#pragma unroll
        for (int q = 0; q < CHK; ++q) {
            const int kk = ch * CHK + q;
            if (kk < NKK2) {
#pragma unroll
                for (int c = 0; c < 5; ++c) {
                    const int ct = wv + 4 * c;
                    if (ct < NCT) {
                        bf16x8 bh = WH[(kk * NCT + ct) * 64 + lane];
                        acc[c] = __builtin_amdgcn_mfma_f32_16x16x32_bf16(a_hi[q], bh, acc[c], 0, 0, 0);
                        acc[c] = __builtin_amdgcn_mfma_f32_16x16x32_bf16(a_lo[q], bh, acc[c], 0, 0, 0);
                    }
                }
            }
        }
    }

    float rs0 = 0.f, rs1 = 0.f, rs2 = 0.f, rs3 = 0.f;
#pragma unroll
    for (int c = 0; c < 5; ++c) {
        const int ct = wv + 4 * c;
        if (ct < NCT) {
            const int k  = ct * 16 + lrow;
            const bool ok = k < HH;
            const int kc = ok ? k : (HH - 1);
            const float iv  = instr[b * HH + kc];
            const float wsv = ok ? w_state[kc] : 0.f;
            rs0 += eluf(acc[c][0] * iv) * wsv;
            rs1 += eluf(acc[c][1] * iv) * wsv;
            rs2 += eluf(acc[c][2] * iv) * wsv;
            rs3 += eluf(acc[c][3] * iv) * wsv;
        }
    }
#pragma unroll
    for (int msk = 1; msk < 16; msk <<= 1) {
        rs0 += __shfl_xor(rs0, msk);
        rs1 += __shfl_xor(rs1, msk);
        rs2 += __shfl_xor(rs2, msk);
        rs3 += __shfl_xor(rs3, msk);
    }
    if (lrow == 0) {
        red[wv][lgrp * 4 + 0] = rs0;
        red[wv][lgrp * 4 + 1] = rs1;
        red[wv][lgrp * 4 + 2] = rs2;
        red[wv][lgrp * 4 + 3] = rs3;
    }
    __syncthreads();
    if (tid < 16) {
        const int n = nt * 16 + tid;
        float v = red[0][tid] + red[1][tid] + red[2][tid] + red[3][tid];
        state_logits[b * NN + n] = v + node_mask[b * NN + n];
    }
}

// ---------------------------------------------------------------------------
// Fallback fp32 node path (used only if ws_size can't hold W_np fragments).
// ---------------------------------------------------------------------------
extern "C" __global__ __launch_bounds__(256)
void node_kernel(const float* __restrict__ node_attr,
                 const float* __restrict__ instr,
                 const float* __restrict__ sim,
                 const float* __restrict__ node_mask,
                 const float* __restrict__ w_np,
                 const float* __restrict__ w_state,
                 float* __restrict__ state_logits)
{
    __shared__ float As[8 * 1200];
    const int b   = (int)blockIdx.x >> 3;
    const int n0  = ((int)blockIdx.x & 7) * 8;
    const int tid = (int)threadIdx.x;
    const int tx  = tid & 31;
    const int r   = tid >> 5;

    {
        const float4* src = reinterpret_cast<const float4*>(
            node_attr + (size_t)(b * NN + n0) * (PP * HH));
        float4* dst = reinterpret_cast<float4*>(As);
#pragma unroll 1
        for (int i = tid; i < 8 * 1200 / 4; i += 256) {
            float4 v = src[i];
            int p = (i % 300) / 75;
            float s = sim[b * PP + p];
            v.x *= s; v.y *= s; v.z *= s; v.w *= s;
            dst[i] = v;
        }
    }
    __syncthreads();

    float spart = 0.f;
    const float4* A4 = reinterpret_cast<const float4*>(As) + r * 300;

#pragma unroll 1
    for (int ct = 0; ct < 3; ++ct) {
        int k0 = ct * 128 + (tx << 2);
        if (k0 + 3 >= HH) continue;
        float acc0 = 0.f, acc1 = 0.f, acc2 = 0.f, acc3 = 0.f;
#pragma unroll 2
        for (int hq = 0; hq < 300; ++hq) {
            float4 a = A4[hq];
            const float* wb = w_np + (size_t)(hq * 4) * HH + k0;
            float4 w0 = *reinterpret_cast<const float4*>(wb);
            float4 w1 = *reinterpret_cast<const float4*>(wb + HH);
            float4 w2 = *reinterpret_cast<const float4*>(wb + 2 * HH);
            float4 w3 = *reinterpret_cast<const float4*>(wb + 3 * HH);
            acc0 = fmaf(a.x, w0.x, fmaf(a.y, w1.x, fmaf(a.z, w2.x, fmaf(a.w, w3.x, acc0))));
            acc1 = fmaf(a.x, w0.y, fmaf(a.y, w1.y, fmaf(a.z, w2.y, fmaf(a.w, w3.y, acc1))));
            acc2 = fmaf(a.x, w0.z, fmaf(a.y, w1.z, fmaf(a.z, w2.z, fmaf(a.w, w3.z, acc2))));
            acc3 = fmaf(a.x, w0.w, fmaf(a.y, w1.w, fmaf(a.z, w2.w, fmaf(a.w, w3.w, acc3))));
        }
        float4 iv  = *reinterpret_cast<const float4*>(instr + b * HH + k0);
        float4 wsv = *reinterpret_cast<const float4*>(w_state + k0);
        spart += eluf(acc0 * iv.x) * wsv.x + eluf(acc1 * iv.y) * wsv.y +
                 eluf(acc2 * iv.z) * wsv.z + eluf(acc3 * iv.w) * wsv.w;
    }

#pragma unroll
    for (int msk = 1; msk < 32; msk <<= 1) spart += __shfl_xor(spart, msk);
    if (tx == 0)
        state_logits[b * NN + n0 + r] = spart + node_mask[b * NN + n0 + r];
}

// ---------------------------------------------------------------------------
// Final: softmax both logit sets over n (one wave per b) and blend.
// ---------------------------------------------------------------------------
extern "C" __global__ __launch_bounds__(64)
void final_kernel(const float* __restrict__ rel_logits,
                  const float* __restrict__ state_logits,
                  const float* __restrict__ rel_sim,
                  float* __restrict__ out)
{
    const int b = (int)blockIdx.x;
    const int n = (int)threadIdx.x;
    float sl = state_logits[b * NN + n];
    float rl = rel_logits[b * NN + n];

    float ms = sl, mr = rl;
#pragma unroll
    for (int msk = 1; msk < 64; msk <<= 1) {
        ms = fmaxf(ms, __shfl_xor(ms, msk));
        mr = fmaxf(mr, __shfl_xor(mr, msk));
    }
    float es = __expf(sl - ms);
    float er = __expf(rl - mr);
    float ss = es, sr = er;
#pragma unroll
    for (int msk = 1; msk < 64; msk <<= 1) {
        ss += __shfl_xor(ss, msk);
        sr += __shfl_xor(sr, msk);
    }
    float rr = rel_sim[b];
    out[b * NN + n] = rr * (er / sr) + (1.f - rr) * (es / ss);
}

extern "C" void kernel_launch(void* const* d_in, const int* in_sizes, int n_in,
                              void* d_out, int out_size, void* d_ws, size_t ws_size,
                              hipStream_t stream) {
    const float* node_attr    = (const float*)d_in[0];
    const float* edge_attr    = (const float*)d_in[1];
    const float* instruction  = (const float*)d_in[2];
    const float* distribution = (const float*)d_in[3];
    const float* node_sim     = (const float*)d_in[4];
    const float* rel_sim      = (const float*)d_in[5];
    const float* node_mask    = (const float*)d_in[6];
    const float* w_np         = (const float*)d_in[7];
    const float* w_edge       = (const float*)d_in[8];
    const float* w_state      = (const float*)d_in[9];
    const float* w_rel        = (const float*)d_in[10];
    float* out = (float*)d_out;

    // workspace layout
    float* rel_ws   = (float*)d_ws;                          // [2048] f32
    float* state_ws = rel_ws + BB * NN;                      // [2048] f32
    char*  wsb      = (char*)d_ws;
    const size_t edge_frag = (size_t)NKK * NCT * 64 * 8 * 2;   // 194,560 B
    const size_t node_frag = (size_t)NKK2 * NCT * 64 * 8 * 2;  // 739,328 B
    short* w_hi  = (short*)(wsb + 16384);
    short* w2_hi = (short*)(wsb + 16384 + edge_frag);
    const size_t need = 16384 + edge_frag + node_frag;
    const bool node_mfma_ok = (ws_size >= need);

    wprep_kernel<<<dim3(NKK * NCT), dim3(64), 0, stream>>>(w_edge, w_hi);

    edge_kernel<<<dim3(BB * NN / 2), dim3(256), 0, stream>>>(
        edge_attr, instruction, distribution, node_mask, w_hi, w_rel, rel_ws);

    if (node_mfma_ok) {
        wprep2_kernel<<<dim3(NKK2 * NCT), dim3(64), 0, stream>>>(w_np, w2_hi);
        node_mfma_kernel<<<dim3(BB * 4), dim3(256), 0, stream>>>(
            node_attr, instruction, node_sim, node_mask, w2_hi,
            w_state, state_ws);
    } else {
        node_kernel<<<dim3(BB * 8), dim3(256), 0, stream>>>(
            node_attr, instruction, node_sim, node_mask, w_np, w_state, state_ws);
    }

    final_kernel<<<dim3(BB), dim3(64), 0, stream>>>(
        rel_ws, state_ws, rel_sim, out);
}

// Round 7
// 155.966 us; speedup vs baseline: 1.1522x; 1.1522x over previous
//
#include <hip/hip_runtime.h>
#include <math.h>

#define BB 32
#define NN 64
#define PP 4
#define HH 300

#define NKK 10    // edge reduction tiles: ceil(300/32)
#define NCT 19    // node output col-tiles of 16: ceil(300/16)
#define NCTE 20   // edge col-tiles PADDED to even (tile 19 = zeros)
#define NPAIR 10  // edge ct-pair iterations
#define NKK2 38   // node reduction tiles: ceil(1200/32)
#define CHK 10    // node kk chunk size (4 chunks cover 38)

typedef float f32x4  __attribute__((ext_vector_type(4)));
typedef short bf16x8 __attribute__((ext_vector_type(8)));

__device__ __forceinline__ float eluf(float x) {
    return x > 0.0f ? x : (__expf(x) - 1.0f);
}

// round-to-nearest-even fp32 -> bf16 bits
__device__ __forceinline__ unsigned short f2bf(float x) {
    unsigned u = __float_as_uint(x);
    u += 0x7FFFu + ((u >> 16) & 1u);
    return (unsigned short)(u >> 16);
}
__device__ __forceinline__ float bf2f(unsigned short s) {
    return __uint_as_float(((unsigned)s) << 16);
}

// ---------------------------------------------------------------------------
// Pre-convert W_edge (300x300 fp32) into MFMA B-fragment-linear bf16 (hi only;
// 2-pass split keeps A fp32-grade, B rounded to bf16):
// tile (kk, ct): lane l, elem j holds W[h][k], h = kk*32 + (l>>4)*8 + j,
// k = ct*16 + (l&15); zero-padded outside 300. NCTE=20 (ct=19 all-zero).
// ---------------------------------------------------------------------------
extern "C" __global__ __launch_bounds__(64)
void wprep_kernel(const float* __restrict__ w_edge,
                  short* __restrict__ w_hi)
{
    const int tile = (int)blockIdx.x;          // kk*NCTE + ct
    const int kk = tile / NCTE, ct = tile % NCTE;
    const int lane = (int)threadIdx.x;
    const int h0 = kk * 32 + (lane >> 4) * 8;
    const int k  = ct * 16 + (lane & 15);
    const size_t base = ((size_t)tile * 64 + lane) * 8;
#pragma unroll
    for (int j = 0; j < 8; ++j) {
        int h = h0 + j;
        float v = (h < HH && k < HH) ? w_edge[h * HH + k] : 0.f;
        w_hi[base + j] = (short)f2bf(v);
    }
}

// Same for W_np flattened to 1200x300 (K index = p*300+h). NCT=19 layout.
extern "C" __global__ __launch_bounds__(64)
void wprep2_kernel(const float* __restrict__ w_np,
                   short* __restrict__ w2_hi)
{
    const int tile = (int)blockIdx.x;          // kk*NCT + ct
    const int kk = tile / NCT, ct = tile % NCT;
    const int lane = (int)threadIdx.x;
    const int h0 = kk * 32 + (lane >> 4) * 8;
    const int k  = ct * 16 + (lane & 15);
    const size_t base = ((size_t)tile * 64 + lane) * 8;
#pragma unroll
    for (int j = 0; j < 8; ++j) {
        int h = h0 + j;
        float v = (h < PP * HH && k < HH) ? w_np[(size_t)h * HH + k] : 0.f;
        w2_hi[base + j] = (short)f2bf(v);
    }
}

// ---------------------------------------------------------------------------
// Edge path via MFMA, 2-pass bf16 split (A fp32-grade, B bf16).
// One block per (b,m); wave wv owns n-rows [16wv,16wv+16).
// ILP redesign (round-6 lesson: A-regs are the occupancy currency):
// process ct-PAIRS -> 4 independent MFMA chains (hi/lo x 2 ct) of length
// 10 sharing the same A fragments. B LDS-staged double-buffered,
// reg-staged (5 tiles/wave/iter), 10 barriers total.
// ---------------------------------------------------------------------------
extern "C" __global__ __launch_bounds__(256)
void edge_kernel(const float* __restrict__ edge_attr,
                 const float* __restrict__ instr,
                 const float* __restrict__ dist,
                 const float* __restrict__ node_mask,
                 const short* __restrict__ w_hi,
                 const float* __restrict__ w_rel,
                 float* __restrict__ rel_logits)
{
    __shared__ __align__(16) short Bs[2][2 * NKK * 512]; // 2 bufs x ct-pair
    __shared__ float red[NN];
    const int b    = (int)blockIdx.x / NN;
    const int m    = (int)blockIdx.x % NN;
    const int tid  = (int)threadIdx.x;
    const int wv   = tid >> 6;
    const int lane = tid & 63;
    const int lrow = lane & 15;
    const int lgrp = lane >> 4;

    // ---- A fragments (hi/lo) into registers, read-once from global ----
    const float* arow = edge_attr
        + (size_t)((b * NN + m) * NN + wv * 16 + lrow) * HH;
    bf16x8 a_hi[NKK], a_lo[NKK];
#pragma unroll
    for (int kk = 0; kk < NKK; ++kk) {
        const int h0 = kk * 32 + lgrp * 8;
        float v[8];
        if (h0 + 7 < HH) {
            f32x4 p0 = *reinterpret_cast<const f32x4*>(arow + h0);
            f32x4 p1 = *reinterpret_cast<const f32x4*>(arow + h0 + 4);
            v[0] = p0[0]; v[1] = p0[1]; v[2] = p0[2]; v[3] = p0[3];
            v[4] = p1[0]; v[5] = p1[1]; v[6] = p1[2]; v[7] = p1[3];
        } else {
#pragma unroll
            for (int j = 0; j < 8; ++j)
                v[j] = (h0 + j < HH) ? arow[h0 + j] : 0.f;
        }
#pragma unroll
        for (int j = 0; j < 8; ++j) {
            unsigned short hb = f2bf(v[j]);
            a_hi[kk][j] = (short)hb;
            a_lo[kk][j] = (short)f2bf(v[j] - bf2f(hb));
        }
    }

    const bf16x8* WH = reinterpret_cast<const bf16x8*>(w_hi);
    const int binst = b * HH;

    // staging: wave wv owns pair-tiles t = wv+4i, i<5 (t<20); t->(c,kk)
    bf16x8 st[5];

    // prologue: stage pair 0 into buf 0
#pragma unroll
    for (int i = 0; i < 5; ++i) {
        const int t = wv + 4 * i;
        const int c = t / NKK, kk = t % NKK;
        st[i] = WH[(kk * NCTE + c) * 64 + lane];
    }
#pragma unroll
    for (int i = 0; i < 5; ++i) {
        const int t = wv + 4 * i;
        const int c = t / NKK, kk = t % NKK;
        *reinterpret_cast<bf16x8*>(&Bs[0][(c * NKK + kk) * 512 + lane * 8]) = st[i];
    }
    __syncthreads();

    float rs0 = 0.f, rs1 = 0.f, rs2 = 0.f, rs3 = 0.f;
    int cur = 0;

#pragma unroll 1
    for (int p = 0; p < NPAIR; ++p) {
        // issue next pair's loads early
        if (p + 1 < NPAIR) {
#pragma unroll
            for (int i = 0; i < 5; ++i) {
                const int t = wv + 4 * i;
                const int c = t / NKK, kk = t % NKK;
                st[i] = WH[(kk * NCTE + 2 * (p + 1) + c) * 64 + lane];
            }
        }

        // compute pair from LDS: 4 independent accumulator chains of 10
        f32x4 aH0 = {0.f, 0.f, 0.f, 0.f};
        f32x4 aL0 = {0.f, 0.f, 0.f, 0.f};
        f32x4 aH1 = {0.f, 0.f, 0.f, 0.f};
        f32x4 aL1 = {0.f, 0.f, 0.f, 0.f};
#pragma unroll
        for (int kk = 0; kk < NKK; ++kk) {
            bf16x8 b0 = *reinterpret_cast<const bf16x8*>(
                &Bs[cur][(0 * NKK + kk) * 512 + lane * 8]);
            bf16x8 b1 = *reinterpret_cast<const bf16x8*>(
                &Bs[cur][(1 * NKK + kk) * 512 + lane * 8]);
            aH0 = __builtin_amdgcn_mfma_f32_16x16x32_bf16(a_hi[kk], b0, aH0, 0, 0, 0);
            aL0 = __builtin_amdgcn_mfma_f32_16x16x32_bf16(a_lo[kk], b0, aL0, 0, 0, 0);
            aH1 = __builtin_amdgcn_mfma_f32_16x16x32_bf16(a_hi[kk], b1, aH1, 0, 0, 0);
            aL1 = __builtin_amdgcn_mfma_f32_16x16x32_bf16(a_lo[kk], b1, aL1, 0, 0, 0);
        }

        // fused epilogue for both ct's of the pair
#pragma unroll
        for (int c = 0; c < 2; ++c) {
            const int k  = (2 * p + c) * 16 + lrow;
            const bool ok = k < HH;
            const int kc = ok ? k : (HH - 1);
            const float iv = instr[binst + kc];
            const float wr = ok ? w_rel[kc] : 0.f;
            const f32x4 aH = c ? aH1 : aH0;
            const f32x4 aL = c ? aL1 : aL0;
            rs0 += eluf((aH[0] + aL[0]) * iv) * wr;
            rs1 += eluf((aH[1] + aL[1]) * iv) * wr;
            rs2 += eluf((aH[2] + aL[2]) * iv) * wr;
            rs3 += eluf((aH[3] + aL[3]) * iv) * wr;
        }

        // write next pair into the other buffer
        if (p + 1 < NPAIR) {
#pragma unroll
            for (int i = 0; i < 5; ++i) {
                const int t = wv + 4 * i;
                const int c = t / NKK, kk = t % NKK;
                *reinterpret_cast<bf16x8*>(
                    &Bs[cur ^ 1][(c * NKK + kk) * 512 + lane * 8]) = st[i];
            }
            __syncthreads();
        }
        cur ^= 1;
    }

    // reduce over the 16 lanes sharing the same C-rows (masks 1,2,4,8)
#pragma unroll
    for (int msk = 1; msk < 16; msk <<= 1) {
        rs0 += __shfl_xor(rs0, msk);
        rs1 += __shfl_xor(rs1, msk);
        rs2 += __shfl_xor(rs2, msk);
        rs3 += __shfl_xor(rs3, msk);
    }
    __syncthreads();   // all waves past last Bs use before red reuse (safety)
    if (lrow == 0) {
        const int r0 = wv * 16 + lgrp * 4;
        red[r0 + 0] = rs0;
        red[r0 + 1] = rs1;
        red[r0 + 2] = rs2;
        red[r0 + 3] = rs3;
    }
    __syncthreads();
    if (tid < 64) {
        float v = red[tid] * dist[b * NN + tid];
#pragma unroll
        for (int msk = 1; msk < 64; msk <<= 1) v += __shfl_xor(v, msk);
        if (tid == 0) rel_logits[b * NN + m] = v + node_mask[b * NN + m];
    }
}

// ---------------------------------------------------------------------------
// Node path via MFMA (2-pass): A[b,n,K=1200] (sim folded) @ Wflat[1200x300].
// One block per (b, 16-row n-tile); 4 waves split the 19 col-tiles.
// ---------------------------------------------------------------------------
extern "C" __global__ __launch_bounds__(256)
void node_mfma_kernel(const float* __restrict__ node_attr,
                      const float* __restrict__ instr,
                      const float* __restrict__ sim,
                      const float* __restrict__ node_mask,
                      const short* __restrict__ w2_hi,
                      const float* __restrict__ w_state,
                      float* __restrict__ state_logits)
{
    __shared__ float red[4][16];
    const int b    = (int)blockIdx.x >> 2;
    const int nt   = (int)blockIdx.x & 3;
    const int tid  = (int)threadIdx.x;
    const int wv   = tid >> 6;
    const int lane = tid & 63;
    const int lrow = lane & 15;
    const int lgrp = lane >> 4;

    const float* arow = node_attr
        + (size_t)(b * NN + nt * 16 + lrow) * (PP * HH);
    float sm[PP];
#pragma unroll
    for (int p = 0; p < PP; ++p) sm[p] = sim[b * PP + p];

    const bf16x8* WH = reinterpret_cast<const bf16x8*>(w2_hi);

    f32x4 acc[5] = {{0.f,0.f,0.f,0.f},{0.f,0.f,0.f,0.f},{0.f,0.f,0.f,0.f},
                    {0.f,0.f,0.f,0.f},{0.f,0.f,0.f,0.f}};

#pragma unroll 1
    for (int ch = 0; ch < 4; ++ch) {
        bf16x8 a_hi[CHK], a_lo[CHK];
#pragma unroll
        for (int q = 0; q < CHK; ++q) {
            const int kk = ch * CHK + q;
            const int h0 = kk * 32 + lgrp * 8;
            float v[8];
            if (kk < NKK2 && h0 + 7 < PP * HH) {
                f32x4 p0 = *reinterpret_cast<const f32x4*>(arow + h0);
                f32x4 p1 = *reinterpret_cast<const f32x4*>(arow + h0 + 4);
                v[0] = p0[0]; v[1] = p0[1]; v[2] = p0[2]; v[3] = p0[3];
                v[4] = p1[0]; v[5] = p1[1]; v[6] = p1[2]; v[7] = p1[3];
            } else {
#pragma unroll
                for (int j = 0; j < 8; ++j)
                    v[j] = (kk < NKK2 && h0 + j < PP * HH) ? arow[h0 + j] : 0.f;
            }
#pragma unroll
            for (int j = 0; j < 8; ++j) {
                const int h = h0 + j;
                const int p = (h < PP * HH) ? (h / HH) : 0;
                float x = v[j] * sm[p];
                unsigned short hb = f2bf(x);
                a_hi[q][j] = (short)hb;
                a_lo[q][j] = (short)f2bf(x - bf2f(hb));
            }
        }
#pragma unroll
        for (int q = 0; q < CHK; ++q) {
            const int kk = ch * CHK + q;
            if (kk < NKK2) {
#pragma unroll
                for (int c = 0; c < 5; ++c) {
                    const int ct = wv + 4 * c;
                    if (ct < NCT) {
                        bf16x8 bh = WH[(kk * NCT + ct) * 64 + lane];
                        acc[c] = __builtin_amdgcn_mfma_f32_16x16x32_bf16(a_hi[q], bh, acc[c], 0, 0, 0);
                        acc[c] = __builtin_amdgcn_mfma_f32_16x16x32_bf16(a_lo[q], bh, acc[c], 0, 0, 0);
                    }
                }
            }
        }
    }

    float rs0 = 0.f, rs1 = 0.f, rs2 = 0.f, rs3 = 0.f;
#pragma unroll
    for (int c = 0; c < 5; ++c) {
        const int ct = wv + 4 * c;
        if (ct < NCT) {
            const int k  = ct * 16 + lrow;
            const bool ok = k < HH;
            const int kc = ok ? k : (HH - 1);
            const float iv  = instr[b * HH + kc];
            const float wsv = ok ? w_state[kc] : 0.f;
            rs0 += eluf(acc[c][0] * iv) * wsv;
            rs1 += eluf(acc[c][1] * iv) * wsv;
            rs2 += eluf(acc[c][2] * iv) * wsv;
            rs3 += eluf(acc[c][3] * iv) * wsv;
        }
    }
#pragma unroll
    for (int msk = 1; msk < 16; msk <<= 1) {
        rs0 += __shfl_xor(rs0, msk);
        rs1 += __shfl_xor(rs1, msk);
        rs2 += __shfl_xor(rs2, msk);
        rs3 += __shfl_xor(rs3, msk);
    }
    if (lrow == 0) {
        red[wv][lgrp * 4 + 0] = rs0;
        red[wv][lgrp * 4 + 1] = rs1;
        red[wv][lgrp * 4 + 2] = rs2;
        red[wv][lgrp * 4 + 3] = rs3;
    }
    __syncthreads();
    if (tid < 16) {
        const int n = nt * 16 + tid;
        float v = red[0][tid] + red[1][tid] + red[2][tid] + red[3][tid];
        state_logits[b * NN + n] = v + node_mask[b * NN + n];
    }
}

// ---------------------------------------------------------------------------
// Fallback fp32 node path (used only if ws_size can't hold W_np fragments).
// ---------------------------------------------------------------------------
extern "C" __global__ __launch_bounds__(256)
void node_kernel(const float* __restrict__ node_attr,
                 const float* __restrict__ instr,
                 const float* __restrict__ sim,
                 const float* __restrict__ node_mask,
                 const float* __restrict__ w_np,
                 const float* __restrict__ w_state,
                 float* __restrict__ state_logits)
{
    __shared__ float As[8 * 1200];
    const int b   = (int)blockIdx.x >> 3;
    const int n0  = ((int)blockIdx.x & 7) * 8;
    const int tid = (int)threadIdx.x;
    const int tx  = tid & 31;
    const int r   = tid >> 5;

    {
        const float4* src = reinterpret_cast<const float4*>(
            node_attr + (size_t)(b * NN + n0) * (PP * HH));
        float4* dst = reinterpret_cast<float4*>(As);
#pragma unroll 1
        for (int i = tid; i < 8 * 1200 / 4; i += 256) {
            float4 v = src[i];
            int p = (i % 300) / 75;
            float s = sim[b * PP + p];
            v.x *= s; v.y *= s; v.z *= s; v.w *= s;
            dst[i] = v;
        }
    }
    __syncthreads();

    float spart = 0.f;
    const float4* A4 = reinterpret_cast<const float4*>(As) + r * 300;

#pragma unroll 1
    for (int ct = 0; ct < 3; ++ct) {
        int k0 = ct * 128 + (tx << 2);
        if (k0 + 3 >= HH) continue;
        float acc0 = 0.f, acc1 = 0.f, acc2 = 0.f, acc3 = 0.f;
#pragma unroll 2
        for (int hq = 0; hq < 300; ++hq) {
            float4 a = A4[hq];
            const float* wb = w_np + (size_t)(hq * 4) * HH + k0;
            float4 w0 = *reinterpret_cast<const float4*>(wb);
            float4 w1 = *reinterpret_cast<const float4*>(wb + HH);
            float4 w2 = *reinterpret_cast<const float4*>(wb + 2 * HH);
            float4 w3 = *reinterpret_cast<const float4*>(wb + 3 * HH);
            acc0 = fmaf(a.x, w0.x, fmaf(a.y, w1.x, fmaf(a.z, w2.x, fmaf(a.w, w3.x, acc0))));
            acc1 = fmaf(a.x, w0.y, fmaf(a.y, w1.y, fmaf(a.z, w2.y, fmaf(a.w, w3.y, acc1))));
            acc2 = fmaf(a.x, w0.z, fmaf(a.y, w1.z, fmaf(a.z, w2.z, fmaf(a.w, w3.z, acc2))));
            acc3 = fmaf(a.x, w0.w, fmaf(a.y, w1.w, fmaf(a.z, w2.w, fmaf(a.w, w3.w, acc3))));
        }
        float4 iv  = *reinterpret_cast<const float4*>(instr + b * HH + k0);
        float4 wsv = *reinterpret_cast<const float4*>(w_state + k0);
        spart += eluf(acc0 * iv.x) * wsv.x + eluf(acc1 * iv.y) * wsv.y +
                 eluf(acc2 * iv.z) * wsv.z + eluf(acc3 * iv.w) * wsv.w;
    }

#pragma unroll
    for (int msk = 1; msk < 32; msk <<= 1) spart += __shfl_xor(spart, msk);
    if (tx == 0)
        state_logits[b * NN + n0 + r] = spart + node_mask[b * NN + n0 + r];
}

// ---------------------------------------------------------------------------
// Final: softmax both logit sets over n (one wave per b) and blend.
// ---------------------------------------------------------------------------
extern "C" __global__ __launch_bounds__(64)
void final_kernel(const float* __restrict__ rel_logits,
                  const float* __restrict__ state_logits,
                  const float* __restrict__ rel_sim,
                  float* __restrict__ out)
{
    const int b = (int)blockIdx.x;
    const int n = (int)threadIdx.x;
    float sl = state_logits[b * NN + n];
    float rl = rel_logits[b * NN + n];

    float ms = sl, mr = rl;
#pragma unroll
    for (int msk = 1; msk < 64; msk <<= 1) {
        ms = fmaxf(ms, __shfl_xor(ms, msk));
        mr = fmaxf(mr, __shfl_xor(mr, msk));
    }
    float es = __expf(sl - ms);
    float er = __expf(rl - mr);
    float ss = es, sr = er;
#pragma unroll
    for (int msk = 1; msk < 64; msk <<= 1) {
        ss += __shfl_xor(ss, msk);
        sr += __shfl_xor(sr, msk);
    }
    float rr = rel_sim[b];
    out[b * NN + n] = rr * (er / sr) + (1.f - rr) * (es / ss);
}

extern "C" void kernel_launch(void* const* d_in, const int* in_sizes, int n_in,
                              void* d_out, int out_size, void* d_ws, size_t ws_size,
                              hipStream_t stream) {
    const float* node_attr    = (const float*)d_in[0];
    const float* edge_attr    = (const float*)d_in[1];
    const float* instruction  = (const float*)d_in[2];
    const float* distribution = (const float*)d_in[3];
    const float* node_sim     = (const float*)d_in[4];
    const float* rel_sim      = (const float*)d_in[5];
    const float* node_mask    = (const float*)d_in[6];
    const float* w_np         = (const float*)d_in[7];
    const float* w_edge       = (const float*)d_in[8];
    const float* w_state      = (const float*)d_in[9];
    const float* w_rel        = (const float*)d_in[10];
    float* out = (float*)d_out;

    // workspace layout
    float* rel_ws   = (float*)d_ws;                           // [2048] f32
    float* state_ws = rel_ws + BB * NN;                       // [2048] f32
    char*  wsb      = (char*)d_ws;
    const size_t edge_frag = (size_t)NKK * NCTE * 64 * 8 * 2;  // 204,800 B
    const size_t node_frag = (size_t)NKK2 * NCT * 64 * 8 * 2;  // 739,328 B
    short* w_hi  = (short*)(wsb + 16384);
    short* w2_hi = (short*)(wsb + 16384 + edge_frag);
    const size_t need = 16384 + edge_frag + node_frag;
    const bool node_mfma_ok = (ws_size >= need);

    wprep_kernel<<<dim3(NKK * NCTE), dim3(64), 0, stream>>>(w_edge, w_hi);

    edge_kernel<<<dim3(BB * NN), dim3(256), 0, stream>>>(
        edge_attr, instruction, distribution, node_mask, w_hi, w_rel, rel_ws);

    if (node_mfma_ok) {
        wprep2_kernel<<<dim3(NKK2 * NCT), dim3(64), 0, stream>>>(w_np, w2_hi);
        node_mfma_kernel<<<dim3(BB * 4), dim3(256), 0, stream>>>(
            node_attr, instruction, node_sim, node_mask, w2_hi,
            w_state, state_ws);
    } else {
        node_kernel<<<dim3(BB * 8), dim3(256), 0, stream>>>(
            node_attr, instruction, node_sim, node_mask, w_np, w_state, state_ws);
    }

    final_kernel<<<dim3(BB), dim3(64), 0, stream>>>(
        rel_ws, state_ws, rel_sim, out);
}

// Round 8
// 149.277 us; speedup vs baseline: 1.2039x; 1.0448x over previous
//
#include <hip/hip_runtime.h>
#include <hip/hip_bf16.h>
#include <math.h>

#define BB 32
#define NN 64
#define PP 4
#define HH 300

#define NKK 10    // edge reduction tiles: ceil(300/32)
#define NCT 19    // node output col-tiles of 16: ceil(300/16)
#define NCTE 20   // edge col-tiles PADDED to even (tile 19 = zeros)
#define NPAIR 10  // edge ct-pair iterations
#define NKK2 38   // node reduction tiles: ceil(1200/32)
#define CHK 10    // node kk chunk size (4 chunks cover 38)

typedef float f32x4  __attribute__((ext_vector_type(4)));
typedef short bf16x8 __attribute__((ext_vector_type(8)));

__device__ __forceinline__ float eluf(float x) {
    return x > 0.0f ? x : (__expf(x) - 1.0f);
}

// fp32 -> bf16 bits via native cvt (compiler emits v_cvt_pk_bf16_f32 pairs)
__device__ __forceinline__ unsigned short f2bf(float x) {
    __hip_bfloat16 h = __float2bfloat16(x);
    unsigned short u;
    __builtin_memcpy(&u, &h, sizeof(u));
    return u;
}
__device__ __forceinline__ float bf2f(unsigned short s) {
    return __uint_as_float(((unsigned)s) << 16);
}

// ---------------------------------------------------------------------------
// Pre-convert W_edge (300x300 fp32) into MFMA B-fragment-linear bf16:
// tile (kk, ct): lane l, elem j holds W[h][k], h = kk*32 + (l>>4)*8 + j,
// k = ct*16 + (l&15); zero-padded outside 300. NCTE=20 (ct=19 all-zero).
// ---------------------------------------------------------------------------
extern "C" __global__ __launch_bounds__(64)
void wprep_kernel(const float* __restrict__ w_edge,
                  short* __restrict__ w_hi)
{
    const int tile = (int)blockIdx.x;          // kk*NCTE + ct
    const int kk = tile / NCTE, ct = tile % NCTE;
    const int lane = (int)threadIdx.x;
    const int h0 = kk * 32 + (lane >> 4) * 8;
    const int k  = ct * 16 + (lane & 15);
    const size_t base = ((size_t)tile * 64 + lane) * 8;
#pragma unroll
    for (int j = 0; j < 8; ++j) {
        int h = h0 + j;
        float v = (h < HH && k < HH) ? w_edge[h * HH + k] : 0.f;
        w_hi[base + j] = (short)f2bf(v);
    }
}

// Same for W_np flattened to 1200x300 (K index = p*300+h). NCT=19 layout.
extern "C" __global__ __launch_bounds__(64)
void wprep2_kernel(const float* __restrict__ w_np,
                   short* __restrict__ w2_hi)
{
    const int tile = (int)blockIdx.x;          // kk*NCT + ct
    const int kk = tile / NCT, ct = tile % NCT;
    const int lane = (int)threadIdx.x;
    const int h0 = kk * 32 + (lane >> 4) * 8;
    const int k  = ct * 16 + (lane & 15);
    const size_t base = ((size_t)tile * 64 + lane) * 8;
#pragma unroll
    for (int j = 0; j < 8; ++j) {
        int h = h0 + j;
        float v = (h < PP * HH && k < HH) ? w_np[(size_t)h * HH + k] : 0.f;
        w2_hi[base + j] = (short)f2bf(v);
    }
}

// ---------------------------------------------------------------------------
// Edge path via MFMA, 2-pass bf16 split (A fp32-grade, B bf16).
// 512-thread blocks, one block per (b, m-PAIR): 8 waves, wave wv handles
// m = m0+(wv>>2), rows 16*(wv&3).. (16 rows/wave keeps A at 80 VGPR —
// round-6 lesson). B LDS-staged (shared by all 8 waves), ct-PAIRS with 4
// independent MFMA chains (round-7 ILP), double-buffered reg staging.
// VALU diet vs round 7: native bf16 cvt (v_cvt_pk) instead of manual RNE
// bit-ops; staging tile->(c,kk) decoded ONCE in prologue, pointers advance
// by constant stride per pair (no div/mod in the loop).
// ---------------------------------------------------------------------------
extern "C" __global__ __launch_bounds__(512)
void edge_kernel(const float* __restrict__ edge_attr,
                 const float* __restrict__ instr,
                 const float* __restrict__ dist,
                 const float* __restrict__ node_mask,
                 const short* __restrict__ w_hi,
                 const float* __restrict__ w_rel,
                 float* __restrict__ rel_logits)
{
    __shared__ __align__(16) short Bs[2][2 * NKK * 512]; // 2 bufs x ct-pair
    __shared__ float red[2][NN];
    const int b    = (int)blockIdx.x / (NN / 2);
    const int mp   = (int)blockIdx.x % (NN / 2);
    const int m0   = 2 * mp;
    const int tid  = (int)threadIdx.x;
    const int wv   = tid >> 6;        // 0..7
    const int lane = tid & 63;
    const int lrow = lane & 15;
    const int lgrp = lane >> 4;
    const int mi   = wv >> 2;         // which m of the pair
    const int rt   = wv & 3;          // 16-row tile within that m

    // ---- A fragments (hi/lo) into registers, read-once from global ----
    const float* arow = edge_attr
        + (size_t)((b * NN + m0 + mi) * NN + rt * 16 + lrow) * HH;
    bf16x8 a_hi[NKK], a_lo[NKK];
#pragma unroll
    for (int kk = 0; kk < NKK; ++kk) {
        const int h0 = kk * 32 + lgrp * 8;
        float v[8];
        if (h0 + 7 < HH) {
            f32x4 p0 = *reinterpret_cast<const f32x4*>(arow + h0);
            f32x4 p1 = *reinterpret_cast<const f32x4*>(arow + h0 + 4);
            v[0] = p0[0]; v[1] = p0[1]; v[2] = p0[2]; v[3] = p0[3];
            v[4] = p1[0]; v[5] = p1[1]; v[6] = p1[2]; v[7] = p1[3];
        } else {
#pragma unroll
            for (int j = 0; j < 8; ++j)
                v[j] = (h0 + j < HH) ? arow[h0 + j] : 0.f;
        }
#pragma unroll
        for (int j = 0; j < 8; ++j) {
            unsigned short hb = f2bf(v[j]);
            a_hi[kk][j] = (short)hb;
            a_lo[kk][j] = (short)f2bf(v[j] - bf2f(hb));
        }
    }

    const bf16x8* WH = reinterpret_cast<const bf16x8*>(w_hi);
    const int binst = b * HH;
    short* BsF = &Bs[0][0];
    const int BUFSTR = 2 * NKK * 512;   // shorts per buffer

    // ---- staging ownership: 20 pair-tiles over 8 waves (3,3,3,3,2,2,2,2)
    // decoded ONCE; pointers advance by constant 128 bf16x8 per pair.
    int nMine, t0;
    if (wv < 4) { nMine = 3; t0 = wv * 3; }
    else        { nMine = 2; t0 = 12 + (wv - 4) * 2; }
    const bf16x8* gp[3];
    int ldst[3];
#pragma unroll
    for (int i = 0; i < 3; ++i) {
        int t  = t0 + (i < nMine ? i : 0);   // clamp to stay in range
        int c  = (t >= NKK) ? 1 : 0;
        int kk = t - c * NKK;
        gp[i]   = WH + ((size_t)kk * NCTE + c) * 64 + lane;
        ldst[i] = (c * NKK + kk) * 512 + lane * 8;
    }

    bf16x8 st[3];
    // prologue: stage pair 0 into buf 0
#pragma unroll
    for (int i = 0; i < 3; ++i)
        if (i < nMine) st[i] = gp[i][0];
#pragma unroll
    for (int i = 0; i < 3; ++i)
        if (i < nMine)
            *reinterpret_cast<bf16x8*>(&BsF[ldst[i]]) = st[i];
#pragma unroll
    for (int i = 0; i < 3; ++i) gp[i] += 128;   // advance to pair 1
    __syncthreads();

    float rs0 = 0.f, rs1 = 0.f, rs2 = 0.f, rs3 = 0.f;
    int cur = 0;

#pragma unroll 1
    for (int p = 0; p < NPAIR; ++p) {
        // issue next pair's loads early
        if (p + 1 < NPAIR) {
#pragma unroll
            for (int i = 0; i < 3; ++i)
                if (i < nMine) st[i] = gp[i][0];
#pragma unroll
            for (int i = 0; i < 3; ++i) gp[i] += 128;
        }

        // compute pair from LDS: 4 independent accumulator chains of 10
        f32x4 aH0 = {0.f, 0.f, 0.f, 0.f};
        f32x4 aL0 = {0.f, 0.f, 0.f, 0.f};
        f32x4 aH1 = {0.f, 0.f, 0.f, 0.f};
        f32x4 aL1 = {0.f, 0.f, 0.f, 0.f};
        const short* bsc = &BsF[cur * BUFSTR + lane * 8];
#pragma unroll
        for (int kk = 0; kk < NKK; ++kk) {
            bf16x8 b0 = *reinterpret_cast<const bf16x8*>(bsc + kk * 512);
            bf16x8 b1 = *reinterpret_cast<const bf16x8*>(bsc + (NKK + kk) * 512);
            aH0 = __builtin_amdgcn_mfma_f32_16x16x32_bf16(a_hi[kk], b0, aH0, 0, 0, 0);
            aL0 = __builtin_amdgcn_mfma_f32_16x16x32_bf16(a_lo[kk], b0, aL0, 0, 0, 0);
            aH1 = __builtin_amdgcn_mfma_f32_16x16x32_bf16(a_hi[kk], b1, aH1, 0, 0, 0);
            aL1 = __builtin_amdgcn_mfma_f32_16x16x32_bf16(a_lo[kk], b1, aL1, 0, 0, 0);
        }

        // fused epilogue for both ct's of the pair
#pragma unroll
        for (int c = 0; c < 2; ++c) {
            const int k  = (2 * p + c) * 16 + lrow;
            const bool ok = k < HH;
            const int kc = ok ? k : (HH - 1);
            const float iv = instr[binst + kc];
            const float wr = ok ? w_rel[kc] : 0.f;
            const f32x4 aH = c ? aH1 : aH0;
            const f32x4 aL = c ? aL1 : aL0;
            rs0 += eluf((aH[0] + aL[0]) * iv) * wr;
            rs1 += eluf((aH[1] + aL[1]) * iv) * wr;
            rs2 += eluf((aH[2] + aL[2]) * iv) * wr;
            rs3 += eluf((aH[3] + aL[3]) * iv) * wr;
        }

        // write next pair into the other buffer
        if (p + 1 < NPAIR) {
#pragma unroll
            for (int i = 0; i < 3; ++i)
                if (i < nMine)
                    *reinterpret_cast<bf16x8*>(
                        &BsF[(cur ^ 1) * BUFSTR + ldst[i]]) = st[i];
            __syncthreads();
        }
        cur ^= 1;
    }

    // reduce over the 16 lanes sharing the same C-rows (masks 1,2,4,8)
#pragma unroll
    for (int msk = 1; msk < 16; msk <<= 1) {
        rs0 += __shfl_xor(rs0, msk);
        rs1 += __shfl_xor(rs1, msk);
        rs2 += __shfl_xor(rs2, msk);
        rs3 += __shfl_xor(rs3, msk);
    }
    if (lrow == 0) {
        const int r0 = rt * 16 + lgrp * 4;
        red[mi][r0 + 0] = rs0;
        red[mi][r0 + 1] = rs1;
        red[mi][r0 + 2] = rs2;
        red[mi][r0 + 3] = rs3;
    }
    __syncthreads();
    if (tid < 128) {
        const int mm = tid >> 6;
        const int ln = tid & 63;
        float v = red[mm][ln] * dist[b * NN + ln];
#pragma unroll
        for (int msk = 1; msk < 64; msk <<= 1) v += __shfl_xor(v, msk);
        if (ln == 0)
            rel_logits[b * NN + m0 + mm] = v + node_mask[b * NN + m0 + mm];
    }
}

// ---------------------------------------------------------------------------
// Node path via MFMA (2-pass): A[b,n,K=1200] (sim folded) @ Wflat[1200x300].
// One block per (b, 16-row n-tile); 4 waves split the 19 col-tiles.
// ---------------------------------------------------------------------------
extern "C" __global__ __launch_bounds__(256)
void node_mfma_kernel(const float* __restrict__ node_attr,
                      const float* __restrict__ instr,
                      const float* __restrict__ sim,
                      const float* __restrict__ node_mask,
                      const short* __restrict__ w2_hi,
                      const float* __restrict__ w_state,
                      float* __restrict__ state_logits)
{
    __shared__ float red[4][16];
    const int b    = (int)blockIdx.x >> 2;
    const int nt   = (int)blockIdx.x & 3;
    const int tid  = (int)threadIdx.x;
    const int wv   = tid >> 6;
    const int lane = tid & 63;
    const int lrow = lane & 15;
    const int lgrp = lane >> 4;

    const float* arow = node_attr
        + (size_t)(b * NN + nt * 16 + lrow) * (PP * HH);
    float sm[PP];
#pragma unroll
    for (int p = 0; p < PP; ++p) sm[p] = sim[b * PP + p];

    const bf16x8* WH = reinterpret_cast<const bf16x8*>(w2_hi);

    f32x4 acc[5] = {{0.f,0.f,0.f,0.f},{0.f,0.f,0.f,0.f},{0.f,0.f,0.f,0.f},
                    {0.f,0.f,0.f,0.f},{0.f,0.f,0.f,0.f}};

#pragma unroll 1
    for (int ch = 0; ch < 4; ++ch) {
        bf16x8 a_hi[CHK], a_lo[CHK];
#pragma unroll
        for (int q = 0; q < CHK; ++q) {
            const int kk = ch * CHK + q;
            const int h0 = kk * 32 + lgrp * 8;
            float v[8];
            if (kk < NKK2 && h0 + 7 < PP * HH) {
                f32x4 p0 = *reinterpret_cast<const f32x4*>(arow + h0);
                f32x4 p1 = *reinterpret_cast<const f32x4*>(arow + h0 + 4);
                v[0] = p0[0]; v[1] = p0[1]; v[2] = p0[2]; v[3] = p0[3];
                v[4] = p1[0]; v[5] = p1[1]; v[6] = p1[2]; v[7] = p1[3];
            } else {
#pragma unroll
                for (int j = 0; j < 8; ++j)
                    v[j] = (kk < NKK2 && h0 + j < PP * HH) ? arow[h0 + j] : 0.f;
            }
#pragma unroll
            for (int j = 0; j < 8; ++j) {
                const int h = h0 + j;
                const int p = (h < PP * HH) ? (h / HH) : 0;
                float x = v[j] * sm[p];
                unsigned short hb = f2bf(x);
                a_hi[q][j] = (short)hb;
                a_lo[q][j] = (short)f2bf(x - bf2f(hb));
            }
        }
#pragma unroll
        for (int q = 0; q < CHK; ++q) {
            const int kk = ch * CHK + q;
            if (kk < NKK2) {
#pragma unroll
                for (int c = 0; c < 5; ++c) {
                    const int ct = wv + 4 * c;
                    if (ct < NCT) {
                        bf16x8 bh = WH[(kk * NCT + ct) * 64 + lane];
                        acc[c] = __builtin_amdgcn_mfma_f32_16x16x32_bf16(a_hi[q], bh, acc[c], 0, 0, 0);
                        acc[c] = __builtin_amdgcn_mfma_f32_16x16x32_bf16(a_lo[q], bh, acc[c], 0, 0, 0);
                    }
                }
            }
        }
    }

    float rs0 = 0.f, rs1 = 0.f, rs2 = 0.f, rs3 = 0.f;
#pragma unroll
    for (int c = 0; c < 5; ++c) {
        const int ct = wv + 4 * c;
        if (ct < NCT) {
            const int k  = ct * 16 + lrow;
            const bool ok = k < HH;
            const int kc = ok ? k : (HH - 1);
            const float iv  = instr[b * HH + kc];
            const float wsv = ok ? w_state[kc] : 0.f;
            rs0 += eluf(acc[c][0] * iv) * wsv;
            rs1 += eluf(acc[c][1] * iv) * wsv;
            rs2 += eluf(acc[c][2] * iv) * wsv;
            rs3 += eluf(acc[c][3] * iv) * wsv;
        }
    }
#pragma unroll
    for (int msk = 1; msk < 16; msk <<= 1) {
        rs0 += __shfl_xor(rs0, msk);
        rs1 += __shfl_xor(rs1, msk);
        rs2 += __shfl_xor(rs2, msk);
        rs3 += __shfl_xor(rs3, msk);
    }
    if (lrow == 0) {
        red[wv][lgrp * 4 + 0] = rs0;
        red[wv][lgrp * 4 + 1] = rs1;
        red[wv][lgrp * 4 + 2] = rs2;
        red[wv][lgrp * 4 + 3] = rs3;
    }
    __syncthreads();
    if (tid < 16) {
        const int n = nt * 16 + tid;
        float v = red[0][tid] + red[1][tid] + red[2][tid] + red[3][tid];
        state_logits[b * NN + n] = v + node_mask[b * NN + n];
    }
}

// ---------------------------------------------------------------------------
// Fallback fp32 node path (used only if ws_size can't hold W_np fragments).
// ---------------------------------------------------------------------------
extern "C" __global__ __launch_bounds__(256)
void node_kernel(const float* __restrict__ node_attr,
                 const float* __restrict__ instr,
                 const float* __restrict__ sim,
                 const float* __restrict__ node_mask,
                 const float* __restrict__ w_np,
                 const float* __restrict__ w_state,
                 float* __restrict__ state_logits)
{
    __shared__ float As[8 * 1200];
    const int b   = (int)blockIdx.x >> 3;
    const int n0  = ((int)blockIdx.x & 7) * 8;
    const int tid = (int)threadIdx.x;
    const int tx  = tid & 31;
    const int r   = tid >> 5;

    {
        const float4* src = reinterpret_cast<const float4*>(
            node_attr + (size_t)(b * NN + n0) * (PP * HH));
        float4* dst = reinterpret_cast<float4*>(As);
#pragma unroll 1
        for (int i = tid; i < 8 * 1200 / 4; i += 256) {
            float4 v = src[i];
            int p = (i % 300) / 75;
            float s = sim[b * PP + p];
            v.x *= s; v.y *= s; v.z *= s; v.w *= s;
            dst[i] = v;
        }
    }
    __syncthreads();

    float spart = 0.f;
    const float4* A4 = reinterpret_cast<const float4*>(As) + r * 300;

#pragma unroll 1
    for (int ct = 0; ct < 3; ++ct) {
        int k0 = ct * 128 + (tx << 2);
        if (k0 + 3 >= HH) continue;
        float acc0 = 0.f, acc1 = 0.f, acc2 = 0.f, acc3 = 0.f;
#pragma unroll 2
        for (int hq = 0; hq < 300; ++hq) {
            float4 a = A4[hq];
            const float* wb = w_np + (size_t)(hq * 4) * HH + k0;
            float4 w0 = *reinterpret_cast<const float4*>(wb);
            float4 w1 = *reinterpret_cast<const float4*>(wb + HH);
            float4 w2 = *reinterpret_cast<const float4*>(wb + 2 * HH);
            float4 w3 = *reinterpret_cast<const float4*>(wb + 3 * HH);
            acc0 = fmaf(a.x, w0.x, fmaf(a.y, w1.x, fmaf(a.z, w2.x, fmaf(a.w, w3.x, acc0))));
            acc1 = fmaf(a.x, w0.y, fmaf(a.y, w1.y, fmaf(a.z, w2.y, fmaf(a.w, w3.y, acc1))));
            acc2 = fmaf(a.x, w0.z, fmaf(a.y, w1.z, fmaf(a.z, w2.z, fmaf(a.w, w3.z, acc2))));
            acc3 = fmaf(a.x, w0.w, fmaf(a.y, w1.w, fmaf(a.z, w2.w, fmaf(a.w, w3.w, acc3))));
        }
        float4 iv  = *reinterpret_cast<const float4*>(instr + b * HH + k0);
        float4 wsv = *reinterpret_cast<const float4*>(w_state + k0);
        spart += eluf(acc0 * iv.x) * wsv.x + eluf(acc1 * iv.y) * wsv.y +
                 eluf(acc2 * iv.z) * wsv.z + eluf(acc3 * iv.w) * wsv.w;
    }

#pragma unroll
    for (int msk = 1; msk < 32; msk <<= 1) spart += __shfl_xor(spart, msk);
    if (tx == 0)
        state_logits[b * NN + n0 + r] = spart + node_mask[b * NN + n0 + r];
}

// ---------------------------------------------------------------------------
// Final: softmax both logit sets over n (one wave per b) and blend.
// ---------------------------------------------------------------------------
extern "C" __global__ __launch_bounds__(64)
void final_kernel(const float* __restrict__ rel_logits,
                  const float* __restrict__ state_logits,
                  const float* __restrict__ rel_sim,
                  float* __restrict__ out)
{
    const int b = (int)blockIdx.x;
    const int n = (int)threadIdx.x;
    float sl = state_logits[b * NN + n];
    float rl = rel_logits[b * NN + n];

    float ms = sl, mr = rl;
#pragma unroll
    for (int msk = 1; msk < 64; msk <<= 1) {
        ms = fmaxf(ms, __shfl_xor(ms, msk));
        mr = fmaxf(mr, __shfl_xor(mr, msk));
    }
    float es = __expf(sl - ms);
    float er = __expf(rl - mr);
    float ss = es, sr = er;
#pragma unroll
    for (int msk = 1; msk < 64; msk <<= 1) {
        ss += __shfl_xor(ss, msk);
        sr += __shfl_xor(sr, msk);
    }
    float rr = rel_sim[b];
    out[b * NN + n] = rr * (er / sr) + (1.f - rr) * (es / ss);
}

extern "C" void kernel_launch(void* const* d_in, const int* in_sizes, int n_in,
                              void* d_out, int out_size, void* d_ws, size_t ws_size,
                              hipStream_t stream) {
    const float* node_attr    = (const float*)d_in[0];
    const float* edge_attr    = (const float*)d_in[1];
    const float* instruction  = (const float*)d_in[2];
    const float* distribution = (const float*)d_in[3];
    const float* node_sim     = (const float*)d_in[4];
    const float* rel_sim      = (const float*)d_in[5];
    const float* node_mask    = (const float*)d_in[6];
    const float* w_np         = (const float*)d_in[7];
    const float* w_edge       = (const float*)d_in[8];
    const float* w_state      = (const float*)d_in[9];
    const float* w_rel        = (const float*)d_in[10];
    float* out = (float*)d_out;

    // workspace layout
    float* rel_ws   = (float*)d_ws;                           // [2048] f32
    float* state_ws = rel_ws + BB * NN;                       // [2048] f32
    char*  wsb      = (char*)d_ws;
    const size_t edge_frag = (size_t)NKK * NCTE * 64 * 8 * 2;  // 204,800 B
    const size_t node_frag = (size_t)NKK2 * NCT * 64 * 8 * 2;  // 739,328 B
    short* w_hi  = (short*)(wsb + 16384);
    short* w2_hi = (short*)(wsb + 16384 + edge_frag);
    const size_t need = 16384 + edge_frag + node_frag;
    const bool node_mfma_ok = (ws_size >= need);

    wprep_kernel<<<dim3(NKK * NCTE), dim3(64), 0, stream>>>(w_edge, w_hi);

    edge_kernel<<<dim3(BB * NN / 2), dim3(512), 0, stream>>>(
        edge_attr, instruction, distribution, node_mask, w_hi, w_rel, rel_ws);

    if (node_mfma_ok) {
        wprep2_kernel<<<dim3(NKK2 * NCT), dim3(64), 0, stream>>>(w_np, w2_hi);
        node_mfma_kernel<<<dim3(BB * 4), dim3(256), 0, stream>>>(
            node_attr, instruction, node_sim, node_mask, w2_hi,
            w_state, state_ws);
    } else {
        node_kernel<<<dim3(BB * 8), dim3(256), 0, stream>>>(
            node_attr, instruction, node_sim, node_mask, w_np, w_state, state_ws);
    }

    final_kernel<<<dim3(BB), dim3(64), 0, stream>>>(
        rel_ws, state_ws, rel_sim, out);
}

// Round 9
// 123.254 us; speedup vs baseline: 1.4580x; 1.2111x over previous
//
#include <hip/hip_runtime.h>
#include <hip/hip_bf16.h>
#include <math.h>

#define BB 32
#define NN 64
#define PP 4
#define HH 300

#define NKK 10    // edge reduction tiles: ceil(300/32)
#define NCT 19    // node output col-tiles of 16: ceil(300/16)
#define NCTE 20   // edge col-tiles PADDED to even (tile 19 = zeros)
#define NPAIR 10  // edge ct-pair iterations
#define NKK2 38   // node reduction tiles: ceil(1200/32)
#define CHK 10    // node kk chunk size (4 chunks cover 38)

typedef float f32x4  __attribute__((ext_vector_type(4)));
typedef short bf16x8 __attribute__((ext_vector_type(8)));

__device__ __forceinline__ float eluf(float x) {
    return x > 0.0f ? x : (__expf(x) - 1.0f);
}

// fp32 -> bf16 bits via native cvt
__device__ __forceinline__ unsigned short f2bf(float x) {
    __hip_bfloat16 h = __float2bfloat16(x);
    unsigned short u;
    __builtin_memcpy(&u, &h, sizeof(u));
    return u;
}

// ---------------------------------------------------------------------------
// Pre-convert W_edge (300x300 fp32) into MFMA B-fragment-linear bf16:
// tile (kk, ct): lane l, elem j holds W[h][k], h = kk*32 + (l>>4)*8 + j,
// k = ct*16 + (l&15); zero-padded outside 300. NCTE=20 (ct=19 all-zero).
// ---------------------------------------------------------------------------
extern "C" __global__ __launch_bounds__(64)
void wprep_kernel(const float* __restrict__ w_edge,
                  short* __restrict__ w_hi)
{
    const int tile = (int)blockIdx.x;          // kk*NCTE + ct
    const int kk = tile / NCTE, ct = tile % NCTE;
    const int lane = (int)threadIdx.x;
    const int h0 = kk * 32 + (lane >> 4) * 8;
    const int k  = ct * 16 + (lane & 15);
    const size_t base = ((size_t)tile * 64 + lane) * 8;
#pragma unroll
    for (int j = 0; j < 8; ++j) {
        int h = h0 + j;
        float v = (h < HH && k < HH) ? w_edge[h * HH + k] : 0.f;
        w_hi[base + j] = (short)f2bf(v);
    }
}

// Same for W_np flattened to 1200x300 (K index = p*300+h). NCT=19 layout.
extern "C" __global__ __launch_bounds__(64)
void wprep2_kernel(const float* __restrict__ w_np,
                   short* __restrict__ w2_hi)
{
    const int tile = (int)blockIdx.x;          // kk*NCT + ct
    const int kk = tile / NCT, ct = tile % NCT;
    const int lane = (int)threadIdx.x;
    const int h0 = kk * 32 + (lane >> 4) * 8;
    const int k  = ct * 16 + (lane & 15);
    const size_t base = ((size_t)tile * 64 + lane) * 8;
#pragma unroll
    for (int j = 0; j < 8; ++j) {
        int h = h0 + j;
        float v = (h < PP * HH && k < HH) ? w_np[(size_t)h * HH + k] : 0.f;
        w2_hi[base + j] = (short)f2bf(v);
    }
}

// ---------------------------------------------------------------------------
// Edge path via MFMA, SINGLE-pass bf16 (A and B both bf16-rounded).
// Accuracy: B-only rounding gave absmax 9.3e-10 (saturated softmax gain
// ~1e-6 from logit to output); A-rounding adds a ~2x logit error factor
// -> predicted absmax ~2e-9, 7 orders under the 2e-2 threshold.
// 512-thread blocks, one block per (b, m-PAIR): wave wv handles
// m = m0+(wv>>2), rows 16*(wv&3).. B LDS-staged (shared by 8 waves),
// ct-PAIRS (2 chains of 10 MFMAs), double-buffered reg staging with
// div/mod-free pointer advance. A-fragments: 40 VGPRs/wave.
// ---------------------------------------------------------------------------
extern "C" __global__ __launch_bounds__(512)
void edge_kernel(const float* __restrict__ edge_attr,
                 const float* __restrict__ instr,
                 const float* __restrict__ dist,
                 const float* __restrict__ node_mask,
                 const short* __restrict__ w_hi,
                 const float* __restrict__ w_rel,
                 float* __restrict__ rel_logits)
{
    __shared__ __align__(16) short Bs[2][2 * NKK * 512]; // 2 bufs x ct-pair
    __shared__ float red[2][NN];
    const int b    = (int)blockIdx.x / (NN / 2);
    const int mp   = (int)blockIdx.x % (NN / 2);
    const int m0   = 2 * mp;
    const int tid  = (int)threadIdx.x;
    const int wv   = tid >> 6;        // 0..7
    const int lane = tid & 63;
    const int lrow = lane & 15;
    const int lgrp = lane >> 4;
    const int mi   = wv >> 2;         // which m of the pair
    const int rt   = wv & 3;          // 16-row tile within that m

    // ---- A fragments (bf16) into registers, read-once from global ----
    const float* arow = edge_attr
        + (size_t)((b * NN + m0 + mi) * NN + rt * 16 + lrow) * HH;
    bf16x8 a_h[NKK];
#pragma unroll
    for (int kk = 0; kk < NKK; ++kk) {
        const int h0 = kk * 32 + lgrp * 8;
        float v[8];
        if (h0 + 7 < HH) {
            f32x4 p0 = *reinterpret_cast<const f32x4*>(arow + h0);
            f32x4 p1 = *reinterpret_cast<const f32x4*>(arow + h0 + 4);
            v[0] = p0[0]; v[1] = p0[1]; v[2] = p0[2]; v[3] = p0[3];
            v[4] = p1[0]; v[5] = p1[1]; v[6] = p1[2]; v[7] = p1[3];
        } else {
#pragma unroll
            for (int j = 0; j < 8; ++j)
                v[j] = (h0 + j < HH) ? arow[h0 + j] : 0.f;
        }
#pragma unroll
        for (int j = 0; j < 8; ++j)
            a_h[kk][j] = (short)f2bf(v[j]);
    }

    const bf16x8* WH = reinterpret_cast<const bf16x8*>(w_hi);
    const int binst = b * HH;
    short* BsF = &Bs[0][0];
    const int BUFSTR = 2 * NKK * 512;   // shorts per buffer

    // ---- staging ownership: 20 pair-tiles over 8 waves (3,3,3,3,2,2,2,2)
    // decoded ONCE; pointers advance by constant 128 bf16x8 per pair.
    int nMine, t0;
    if (wv < 4) { nMine = 3; t0 = wv * 3; }
    else        { nMine = 2; t0 = 12 + (wv - 4) * 2; }
    const bf16x8* gp[3];
    int ldst[3];
#pragma unroll
    for (int i = 0; i < 3; ++i) {
        int t  = t0 + (i < nMine ? i : 0);   // clamp to stay in range
        int c  = (t >= NKK) ? 1 : 0;
        int kk = t - c * NKK;
        gp[i]   = WH + ((size_t)kk * NCTE + c) * 64 + lane;
        ldst[i] = (c * NKK + kk) * 512 + lane * 8;
    }

    bf16x8 st[3];
    // prologue: stage pair 0 into buf 0
#pragma unroll
    for (int i = 0; i < 3; ++i)
        if (i < nMine) st[i] = gp[i][0];
#pragma unroll
    for (int i = 0; i < 3; ++i)
        if (i < nMine)
            *reinterpret_cast<bf16x8*>(&BsF[ldst[i]]) = st[i];
#pragma unroll
    for (int i = 0; i < 3; ++i) gp[i] += 128;   // advance to pair 1
    __syncthreads();

    float rs0 = 0.f, rs1 = 0.f, rs2 = 0.f, rs3 = 0.f;
    int cur = 0;

#pragma unroll 1
    for (int p = 0; p < NPAIR; ++p) {
        // issue next pair's loads early
        if (p + 1 < NPAIR) {
#pragma unroll
            for (int i = 0; i < 3; ++i)
                if (i < nMine) st[i] = gp[i][0];
#pragma unroll
            for (int i = 0; i < 3; ++i) gp[i] += 128;
        }

        // compute pair from LDS: 2 independent accumulator chains of 10
        f32x4 aH0 = {0.f, 0.f, 0.f, 0.f};
        f32x4 aH1 = {0.f, 0.f, 0.f, 0.f};
        const short* bsc = &BsF[cur * BUFSTR + lane * 8];
#pragma unroll
        for (int kk = 0; kk < NKK; ++kk) {
            bf16x8 b0 = *reinterpret_cast<const bf16x8*>(bsc + kk * 512);
            bf16x8 b1 = *reinterpret_cast<const bf16x8*>(bsc + (NKK + kk) * 512);
            aH0 = __builtin_amdgcn_mfma_f32_16x16x32_bf16(a_h[kk], b0, aH0, 0, 0, 0);
            aH1 = __builtin_amdgcn_mfma_f32_16x16x32_bf16(a_h[kk], b1, aH1, 0, 0, 0);
        }

        // fused epilogue for both ct's of the pair
#pragma unroll
        for (int c = 0; c < 2; ++c) {
            const int k  = (2 * p + c) * 16 + lrow;
            const bool ok = k < HH;
            const int kc = ok ? k : (HH - 1);
            const float iv = instr[binst + kc];
            const float wr = ok ? w_rel[kc] : 0.f;
            const f32x4 aH = c ? aH1 : aH0;
            rs0 += eluf(aH[0] * iv) * wr;
            rs1 += eluf(aH[1] * iv) * wr;
            rs2 += eluf(aH[2] * iv) * wr;
            rs3 += eluf(aH[3] * iv) * wr;
        }

        // write next pair into the other buffer
        if (p + 1 < NPAIR) {
#pragma unroll
            for (int i = 0; i < 3; ++i)
                if (i < nMine)
                    *reinterpret_cast<bf16x8*>(
                        &BsF[(cur ^ 1) * BUFSTR + ldst[i]]) = st[i];
            __syncthreads();
        }
        cur ^= 1;
    }

    // reduce over the 16 lanes sharing the same C-rows (masks 1,2,4,8)
#pragma unroll
    for (int msk = 1; msk < 16; msk <<= 1) {
        rs0 += __shfl_xor(rs0, msk);
        rs1 += __shfl_xor(rs1, msk);
        rs2 += __shfl_xor(rs2, msk);
        rs3 += __shfl_xor(rs3, msk);
    }
    if (lrow == 0) {
        const int r0 = rt * 16 + lgrp * 4;
        red[mi][r0 + 0] = rs0;
        red[mi][r0 + 1] = rs1;
        red[mi][r0 + 2] = rs2;
        red[mi][r0 + 3] = rs3;
    }
    __syncthreads();
    if (tid < 128) {
        const int mm = tid >> 6;
        const int ln = tid & 63;
        float v = red[mm][ln] * dist[b * NN + ln];
#pragma unroll
        for (int msk = 1; msk < 64; msk <<= 1) v += __shfl_xor(v, msk);
        if (ln == 0)
            rel_logits[b * NN + m0 + mm] = v + node_mask[b * NN + m0 + mm];
    }
}

// ---------------------------------------------------------------------------
// Node path via MFMA, SINGLE-pass bf16: A[b,n,K=1200] (sim folded) @
// Wflat[1200x300]. One block per (b, 16-row n-tile); 4 waves split the
// 19 col-tiles (5 independent acc chains per wave).
// ---------------------------------------------------------------------------
extern "C" __global__ __launch_bounds__(256)
void node_mfma_kernel(const float* __restrict__ node_attr,
                      const float* __restrict__ instr,
                      const float* __restrict__ sim,
                      const float* __restrict__ node_mask,
                      const short* __restrict__ w2_hi,
                      const float* __restrict__ w_state,
                      float* __restrict__ state_logits)
{
    __shared__ float red[4][16];
    const int b    = (int)blockIdx.x >> 2;
    const int nt   = (int)blockIdx.x & 3;
    const int tid  = (int)threadIdx.x;
    const int wv   = tid >> 6;
    const int lane = tid & 63;
    const int lrow = lane & 15;
    const int lgrp = lane >> 4;

    const float* arow = node_attr
        + (size_t)(b * NN + nt * 16 + lrow) * (PP * HH);
    float sm[PP];
#pragma unroll
    for (int p = 0; p < PP; ++p) sm[p] = sim[b * PP + p];

    const bf16x8* WH = reinterpret_cast<const bf16x8*>(w2_hi);

    f32x4 acc[5] = {{0.f,0.f,0.f,0.f},{0.f,0.f,0.f,0.f},{0.f,0.f,0.f,0.f},
                    {0.f,0.f,0.f,0.f},{0.f,0.f,0.f,0.f}};

#pragma unroll 1
    for (int ch = 0; ch < 4; ++ch) {
        bf16x8 a_h[CHK];
#pragma unroll
        for (int q = 0; q < CHK; ++q) {
            const int kk = ch * CHK + q;
            const int h0 = kk * 32 + lgrp * 8;
            float v[8];
            if (kk < NKK2 && h0 + 7 < PP * HH) {
                f32x4 p0 = *reinterpret_cast<const f32x4*>(arow + h0);
                f32x4 p1 = *reinterpret_cast<const f32x4*>(arow + h0 + 4);
                v[0] = p0[0]; v[1] = p0[1]; v[2] = p0[2]; v[3] = p0[3];
                v[4] = p1[0]; v[5] = p1[1]; v[6] = p1[2]; v[7] = p1[3];
            } else {
#pragma unroll
                for (int j = 0; j < 8; ++j)
                    v[j] = (kk < NKK2 && h0 + j < PP * HH) ? arow[h0 + j] : 0.f;
            }
#pragma unroll
            for (int j = 0; j < 8; ++j) {
                const int h = h0 + j;
                const int p = (h < PP * HH) ? (h / HH) : 0;
                a_h[q][j] = (short)f2bf(v[j] * sm[p]);
            }
        }
#pragma unroll
        for (int q = 0; q < CHK; ++q) {
            const int kk = ch * CHK + q;
            if (kk < NKK2) {
#pragma unroll
                for (int c = 0; c < 5; ++c) {
                    const int ct = wv + 4 * c;
                    if (ct < NCT) {
                        bf16x8 bh = WH[(kk * NCT + ct) * 64 + lane];
                        acc[c] = __builtin_amdgcn_mfma_f32_16x16x32_bf16(a_h[q], bh, acc[c], 0, 0, 0);
                    }
                }
            }
        }
    }

    float rs0 = 0.f, rs1 = 0.f, rs2 = 0.f, rs3 = 0.f;
#pragma unroll
    for (int c = 0; c < 5; ++c) {
        const int ct = wv + 4 * c;
        if (ct < NCT) {
            const int k  = ct * 16 + lrow;
            const bool ok = k < HH;
            const int kc = ok ? k : (HH - 1);
            const float iv  = instr[b * HH + kc];
            const float wsv = ok ? w_state[kc] : 0.f;
            rs0 += eluf(acc[c][0] * iv) * wsv;
            rs1 += eluf(acc[c][1] * iv) * wsv;
            rs2 += eluf(acc[c][2] * iv) * wsv;
            rs3 += eluf(acc[c][3] * iv) * wsv;
        }
    }
#pragma unroll
    for (int msk = 1; msk < 16; msk <<= 1) {
        rs0 += __shfl_xor(rs0, msk);
        rs1 += __shfl_xor(rs1, msk);
        rs2 += __shfl_xor(rs2, msk);
        rs3 += __shfl_xor(rs3, msk);
    }
    if (lrow == 0) {
        red[wv][lgrp * 4 + 0] = rs0;
        red[wv][lgrp * 4 + 1] = rs1;
        red[wv][lgrp * 4 + 2] = rs2;
        red[wv][lgrp * 4 + 3] = rs3;
    }
    __syncthreads();
    if (tid < 16) {
        const int n = nt * 16 + tid;
        float v = red[0][tid] + red[1][tid] + red[2][tid] + red[3][tid];
        state_logits[b * NN + n] = v + node_mask[b * NN + n];
    }
}

// ---------------------------------------------------------------------------
// Fallback fp32 node path (used only if ws_size can't hold W_np fragments).
// ---------------------------------------------------------------------------
extern "C" __global__ __launch_bounds__(256)
void node_kernel(const float* __restrict__ node_attr,
                 const float* __restrict__ instr,
                 const float* __restrict__ sim,
                 const float* __restrict__ node_mask,
                 const float* __restrict__ w_np,
                 const float* __restrict__ w_state,
                 float* __restrict__ state_logits)
{
    __shared__ float As[8 * 1200];
    const int b   = (int)blockIdx.x >> 3;
    const int n0  = ((int)blockIdx.x & 7) * 8;
    const int tid = (int)threadIdx.x;
    const int tx  = tid & 31;
    const int r   = tid >> 5;

    {
        const float4* src = reinterpret_cast<const float4*>(
            node_attr + (size_t)(b * NN + n0) * (PP * HH));
        float4* dst = reinterpret_cast<float4*>(As);
#pragma unroll 1
        for (int i = tid; i < 8 * 1200 / 4; i += 256) {
            float4 v = src[i];
            int p = (i % 300) / 75;
            float s = sim[b * PP + p];
            v.x *= s; v.y *= s; v.z *= s; v.w *= s;
            dst[i] = v;
        }
    }
    __syncthreads();

    float spart = 0.f;
    const float4* A4 = reinterpret_cast<const float4*>(As) + r * 300;

#pragma unroll 1
    for (int ct = 0; ct < 3; ++ct) {
        int k0 = ct * 128 + (tx << 2);
        if (k0 + 3 >= HH) continue;
        float acc0 = 0.f, acc1 = 0.f, acc2 = 0.f, acc3 = 0.f;
#pragma unroll 2
        for (int hq = 0; hq < 300; ++hq) {
            float4 a = A4[hq];
            const float* wb = w_np + (size_t)(hq * 4) * HH + k0;
            float4 w0 = *reinterpret_cast<const float4*>(wb);
            float4 w1 = *reinterpret_cast<const float4*>(wb + HH);
            float4 w2 = *reinterpret_cast<const float4*>(wb + 2 * HH);
            float4 w3 = *reinterpret_cast<const float4*>(wb + 3 * HH);
            acc0 = fmaf(a.x, w0.x, fmaf(a.y, w1.x, fmaf(a.z, w2.x, fmaf(a.w, w3.x, acc0))));
            acc1 = fmaf(a.x, w0.y, fmaf(a.y, w1.y, fmaf(a.z, w2.y, fmaf(a.w, w3.y, acc1))));
            acc2 = fmaf(a.x, w0.z, fmaf(a.y, w1.z, fmaf(a.z, w2.z, fmaf(a.w, w3.z, acc2))));
            acc3 = fmaf(a.x, w0.w, fmaf(a.y, w1.w, fmaf(a.z, w2.w, fmaf(a.w, w3.w, acc3))));
        }
        float4 iv  = *reinterpret_cast<const float4*>(instr + b * HH + k0);
        float4 wsv = *reinterpret_cast<const float4*>(w_state + k0);
        spart += eluf(acc0 * iv.x) * wsv.x + eluf(acc1 * iv.y) * wsv.y +
                 eluf(acc2 * iv.z) * wsv.z + eluf(acc3 * iv.w) * wsv.w;
    }

#pragma unroll
    for (int msk = 1; msk < 32; msk <<= 1) spart += __shfl_xor(spart, msk);
    if (tx == 0)
        state_logits[b * NN + n0 + r] = spart + node_mask[b * NN + n0 + r];
}

// ---------------------------------------------------------------------------
// Final: softmax both logit sets over n (one wave per b) and blend.
// ---------------------------------------------------------------------------
extern "C" __global__ __launch_bounds__(64)
void final_kernel(const float* __restrict__ rel_logits,
                  const float* __restrict__ state_logits,
                  const float* __restrict__ rel_sim,
                  float* __restrict__ out)
{
    const int b = (int)blockIdx.x;
    const int n = (int)threadIdx.x;
    float sl = state_logits[b * NN + n];
    float rl = rel_logits[b * NN + n];

    float ms = sl, mr = rl;
#pragma unroll
    for (int msk = 1; msk < 64; msk <<= 1) {
        ms = fmaxf(ms, __shfl_xor(ms, msk));
        mr = fmaxf(mr, __shfl_xor(mr, msk));
    }
    float es = __expf(sl - ms);
    float er = __expf(rl - mr);
    float ss = es, sr = er;
#pragma unroll
    for (int msk = 1; msk < 64; msk <<= 1) {
        ss += __shfl_xor(ss, msk);
        sr += __shfl_xor(sr, msk);
    }
    float rr = rel_sim[b];
    out[b * NN + n] = rr * (er / sr) + (1.f - rr) * (es / ss);
}

extern "C" void kernel_launch(void* const* d_in, const int* in_sizes, int n_in,
                              void* d_out, int out_size, void* d_ws, size_t ws_size,
                              hipStream_t stream) {
    const float* node_attr    = (const float*)d_in[0];
    const float* edge_attr    = (const float*)d_in[1];
    const float* instruction  = (const float*)d_in[2];
    const float* distribution = (const float*)d_in[3];
    const float* node_sim     = (const float*)d_in[4];
    const float* rel_sim      = (const float*)d_in[5];
    const float* node_mask    = (const float*)d_in[6];
    const float* w_np         = (const float*)d_in[7];
    const float* w_edge       = (const float*)d_in[8];
    const float* w_state      = (const float*)d_in[9];
    const float* w_rel        = (const float*)d_in[10];
    float* out = (float*)d_out;

    // workspace layout
    float* rel_ws   = (float*)d_ws;                           // [2048] f32
    float* state_ws = rel_ws + BB * NN;                       // [2048] f32
    char*  wsb      = (char*)d_ws;
    const size_t edge_frag = (size_t)NKK * NCTE * 64 * 8 * 2;  // 204,800 B
    const size_t node_frag = (size_t)NKK2 * NCT * 64 * 8 * 2;  // 739,328 B
    short* w_hi  = (short*)(wsb + 16384);
    short* w2_hi = (short*)(wsb + 16384 + edge_frag);
    const size_t need = 16384 + edge_frag + node_frag;
    const bool node_mfma_ok = (ws_size >= need);

    wprep_kernel<<<dim3(NKK * NCTE), dim3(64), 0, stream>>>(w_edge, w_hi);

    edge_kernel<<<dim3(BB * NN / 2), dim3(512), 0, stream>>>(
        edge_attr, instruction, distribution, node_mask, w_hi, w_rel, rel_ws);

    if (node_mfma_ok) {
        wprep2_kernel<<<dim3(NKK2 * NCT), dim3(64), 0, stream>>>(w_np, w2_hi);
        node_mfma_kernel<<<dim3(BB * 4), dim3(256), 0, stream>>>(
            node_attr, instruction, node_sim, node_mask, w2_hi,
            w_state, state_ws);
    } else {
        node_kernel<<<dim3(BB * 8), dim3(256), 0, stream>>>(
            node_attr, instruction, node_sim, node_mask, w_np, w_state, state_ws);
    }

    final_kernel<<<dim3(BB), dim3(64), 0, stream>>>(
        rel_ws, state_ws, rel_sim, out);
}

// Round 10
// 123.174 us; speedup vs baseline: 1.4590x; 1.0007x over previous
//
#include <hip/hip_runtime.h>
#include <math.h>

#define BB 32
#define NN 64
#define PP 4
#define HH 300

#define NKK 10    // edge reduction tiles: ceil(300/32)
#define NCT 19    // node output col-tiles of 16: ceil(300/16)
#define NCTE 20   // edge col-tiles PADDED to even (tile 19 = zeros)
#define NPAIR 10  // edge ct-pair iterations
#define NKK2 38   // node reduction tiles: ceil(1200/32)
#define CHK 10    // node kk chunk size (4 chunks cover 38)

typedef float    f32x4 __attribute__((ext_vector_type(4)));
typedef _Float16 f16x8 __attribute__((ext_vector_type(8)));

__device__ __forceinline__ float eluf(float x) {
    return x > 0.0f ? x : (__expf(x) - 1.0f);
}

// ---------------------------------------------------------------------------
// Pre-convert W_edge (300x300 fp32) into MFMA B-fragment-linear FP16
// (fp16 single-pass: 2^-11 input rounding vs bf16's 2^-8 — round-9 lesson:
// bf16 single-pass landed at 97% of the absmax threshold).
// tile (kk, ct): lane l, elem j holds W[h][k], h = kk*32 + (l>>4)*8 + j,
// k = ct*16 + (l&15); zero-padded outside 300. NCTE=20 (ct=19 all-zero).
// ---------------------------------------------------------------------------
extern "C" __global__ __launch_bounds__(64)
void wprep_kernel(const float* __restrict__ w_edge,
                  _Float16* __restrict__ w_hi)
{
    const int tile = (int)blockIdx.x;          // kk*NCTE + ct
    const int kk = tile / NCTE, ct = tile % NCTE;
    const int lane = (int)threadIdx.x;
    const int h0 = kk * 32 + (lane >> 4) * 8;
    const int k  = ct * 16 + (lane & 15);
    const size_t base = ((size_t)tile * 64 + lane) * 8;
#pragma unroll
    for (int j = 0; j < 8; ++j) {
        int h = h0 + j;
        float v = (h < HH && k < HH) ? w_edge[h * HH + k] : 0.f;
        w_hi[base + j] = (_Float16)v;
    }
}

// Same for W_np flattened to 1200x300 (K index = p*300+h). NCT=19 layout.
extern "C" __global__ __launch_bounds__(64)
void wprep2_kernel(const float* __restrict__ w_np,
                   _Float16* __restrict__ w2_hi)
{
    const int tile = (int)blockIdx.x;          // kk*NCT + ct
    const int kk = tile / NCT, ct = tile % NCT;
    const int lane = (int)threadIdx.x;
    const int h0 = kk * 32 + (lane >> 4) * 8;
    const int k  = ct * 16 + (lane & 15);
    const size_t base = ((size_t)tile * 64 + lane) * 8;
#pragma unroll
    for (int j = 0; j < 8; ++j) {
        int h = h0 + j;
        float v = (h < PP * HH && k < HH) ? w_np[(size_t)h * HH + k] : 0.f;
        w2_hi[base + j] = (_Float16)v;
    }
}

// ---------------------------------------------------------------------------
// Edge path via MFMA, SINGLE-pass FP16 (A and B fp16-rounded, fp32 acc).
// Accuracy: bf16 single-pass measured absmax 0.0195 (97% of threshold);
// fp16's 8x smaller input rounding (2^-11 vs 2^-8) -> predicted ~2.4e-3.
// Range safe: inputs ~N(0,1), weights exactly representable.
// 512-thread blocks, one block per (b, m-PAIR): wave wv handles
// m = m0+(wv>>2), rows 16*(wv&3).. B LDS-staged (shared by 8 waves),
// ct-PAIRS (2 chains of 10 MFMAs), double-buffered reg staging with
// div/mod-free pointer advance. A-fragments: 40 VGPRs/wave.
// ---------------------------------------------------------------------------
extern "C" __global__ __launch_bounds__(512)
void edge_kernel(const float* __restrict__ edge_attr,
                 const float* __restrict__ instr,
                 const float* __restrict__ dist,
                 const float* __restrict__ node_mask,
                 const _Float16* __restrict__ w_hi,
                 const float* __restrict__ w_rel,
                 float* __restrict__ rel_logits)
{
    __shared__ __align__(16) _Float16 Bs[2][2 * NKK * 512]; // 2 bufs x ct-pair
    __shared__ float red[2][NN];
    const int b    = (int)blockIdx.x / (NN / 2);
    const int mp   = (int)blockIdx.x % (NN / 2);
    const int m0   = 2 * mp;
    const int tid  = (int)threadIdx.x;
    const int wv   = tid >> 6;        // 0..7
    const int lane = tid & 63;
    const int lrow = lane & 15;
    const int lgrp = lane >> 4;
    const int mi   = wv >> 2;         // which m of the pair
    const int rt   = wv & 3;          // 16-row tile within that m

    // ---- A fragments (fp16) into registers, read-once from global ----
    const float* arow = edge_attr
        + (size_t)((b * NN + m0 + mi) * NN + rt * 16 + lrow) * HH;
    f16x8 a_h[NKK];
#pragma unroll
    for (int kk = 0; kk < NKK; ++kk) {
        const int h0 = kk * 32 + lgrp * 8;
        float v[8];
        if (h0 + 7 < HH) {
            f32x4 p0 = *reinterpret_cast<const f32x4*>(arow + h0);
            f32x4 p1 = *reinterpret_cast<const f32x4*>(arow + h0 + 4);
            v[0] = p0[0]; v[1] = p0[1]; v[2] = p0[2]; v[3] = p0[3];
            v[4] = p1[0]; v[5] = p1[1]; v[6] = p1[2]; v[7] = p1[3];
        } else {
#pragma unroll
            for (int j = 0; j < 8; ++j)
                v[j] = (h0 + j < HH) ? arow[h0 + j] : 0.f;
        }
#pragma unroll
        for (int j = 0; j < 8; ++j)
            a_h[kk][j] = (_Float16)v[j];
    }

    const f16x8* WH = reinterpret_cast<const f16x8*>(w_hi);
    const int binst = b * HH;
    _Float16* BsF = &Bs[0][0];
    const int BUFSTR = 2 * NKK * 512;   // fp16 elems per buffer

    // ---- staging ownership: 20 pair-tiles over 8 waves (3,3,3,3,2,2,2,2)
    // decoded ONCE; pointers advance by constant 128 f16x8 per pair.
    int nMine, t0;
    if (wv < 4) { nMine = 3; t0 = wv * 3; }
    else        { nMine = 2; t0 = 12 + (wv - 4) * 2; }
    const f16x8* gp[3];
    int ldst[3];
#pragma unroll
    for (int i = 0; i < 3; ++i) {
        int t  = t0 + (i < nMine ? i : 0);   // clamp to stay in range
        int c  = (t >= NKK) ? 1 : 0;
        int kk = t - c * NKK;
        gp[i]   = WH + ((size_t)kk * NCTE + c) * 64 + lane;
        ldst[i] = (c * NKK + kk) * 512 + lane * 8;
    }

    f16x8 st[3];
    // prologue: stage pair 0 into buf 0
#pragma unroll
    for (int i = 0; i < 3; ++i)
        if (i < nMine) st[i] = gp[i][0];
#pragma unroll
    for (int i = 0; i < 3; ++i)
        if (i < nMine)
            *reinterpret_cast<f16x8*>(&BsF[ldst[i]]) = st[i];
#pragma unroll
    for (int i = 0; i < 3; ++i) gp[i] += 128;   // advance to pair 1
    __syncthreads();

    float rs0 = 0.f, rs1 = 0.f, rs2 = 0.f, rs3 = 0.f;
    int cur = 0;

#pragma unroll 1
    for (int p = 0; p < NPAIR; ++p) {
        // issue next pair's loads early
        if (p + 1 < NPAIR) {
#pragma unroll
            for (int i = 0; i < 3; ++i)
                if (i < nMine) st[i] = gp[i][0];
#pragma unroll
            for (int i = 0; i < 3; ++i) gp[i] += 128;
        }

        // compute pair from LDS: 2 independent accumulator chains of 10
        f32x4 aH0 = {0.f, 0.f, 0.f, 0.f};
        f32x4 aH1 = {0.f, 0.f, 0.f, 0.f};
        const _Float16* bsc = &BsF[cur * BUFSTR + lane * 8];
#pragma unroll
        for (int kk = 0; kk < NKK; ++kk) {
            f16x8 b0 = *reinterpret_cast<const f16x8*>(bsc + kk * 512);
            f16x8 b1 = *reinterpret_cast<const f16x8*>(bsc + (NKK + kk) * 512);
            aH0 = __builtin_amdgcn_mfma_f32_16x16x32_f16(a_h[kk], b0, aH0, 0, 0, 0);
            aH1 = __builtin_amdgcn_mfma_f32_16x16x32_f16(a_h[kk], b1, aH1, 0, 0, 0);
        }

        // fused epilogue for both ct's of the pair
#pragma unroll
        for (int c = 0; c < 2; ++c) {
            const int k  = (2 * p + c) * 16 + lrow;
            const bool ok = k < HH;
            const int kc = ok ? k : (HH - 1);
            const float iv = instr[binst + kc];
            const float wr = ok ? w_rel[kc] : 0.f;
            const f32x4 aH = c ? aH1 : aH0;
            rs0 += eluf(aH[0] * iv) * wr;
            rs1 += eluf(aH[1] * iv) * wr;
            rs2 += eluf(aH[2] * iv) * wr;
            rs3 += eluf(aH[3] * iv) * wr;
        }

        // write next pair into the other buffer
        if (p + 1 < NPAIR) {
#pragma unroll
            for (int i = 0; i < 3; ++i)
                if (i < nMine)
                    *reinterpret_cast<f16x8*>(
                        &BsF[(cur ^ 1) * BUFSTR + ldst[i]]) = st[i];
            __syncthreads();
        }
        cur ^= 1;
    }

    // reduce over the 16 lanes sharing the same C-rows (masks 1,2,4,8)
#pragma unroll
    for (int msk = 1; msk < 16; msk <<= 1) {
        rs0 += __shfl_xor(rs0, msk);
        rs1 += __shfl_xor(rs1, msk);
        rs2 += __shfl_xor(rs2, msk);
        rs3 += __shfl_xor(rs3, msk);
    }
    if (lrow == 0) {
        const int r0 = rt * 16 + lgrp * 4;
        red[mi][r0 + 0] = rs0;
        red[mi][r0 + 1] = rs1;
        red[mi][r0 + 2] = rs2;
        red[mi][r0 + 3] = rs3;
    }
    __syncthreads();
    if (tid < 128) {
        const int mm = tid >> 6;
        const int ln = tid & 63;
        float v = red[mm][ln] * dist[b * NN + ln];
#pragma unroll
        for (int msk = 1; msk < 64; msk <<= 1) v += __shfl_xor(v, msk);
        if (ln == 0)
            rel_logits[b * NN + m0 + mm] = v + node_mask[b * NN + m0 + mm];
    }
}

// ---------------------------------------------------------------------------
// Node path via MFMA, SINGLE-pass FP16: A[b,n,K=1200] (sim folded) @
// Wflat[1200x300]. One block per (b, 16-row n-tile); 4 waves split the
// 19 col-tiles (5 independent acc chains per wave).
// ---------------------------------------------------------------------------
extern "C" __global__ __launch_bounds__(256)
void node_mfma_kernel(const float* __restrict__ node_attr,
                      const float* __restrict__ instr,
                      const float* __restrict__ sim,
                      const float* __restrict__ node_mask,
                      const _Float16* __restrict__ w2_hi,
                      const float* __restrict__ w_state,
                      float* __restrict__ state_logits)
{
    __shared__ float red[4][16];
    const int b    = (int)blockIdx.x >> 2;
    const int nt   = (int)blockIdx.x & 3;
    const int tid  = (int)threadIdx.x;
    const int wv   = tid >> 6;
    const int lane = tid & 63;
    const int lrow = lane & 15;
    const int lgrp = lane >> 4;

    const float* arow = node_attr
        + (size_t)(b * NN + nt * 16 + lrow) * (PP * HH);
    float sm[PP];
#pragma unroll
    for (int p = 0; p < PP; ++p) sm[p] = sim[b * PP + p];

    const f16x8* WH = reinterpret_cast<const f16x8*>(w2_hi);

    f32x4 acc[5] = {{0.f,0.f,0.f,0.f},{0.f,0.f,0.f,0.f},{0.f,0.f,0.f,0.f},
                    {0.f,0.f,0.f,0.f},{0.f,0.f,0.f,0.f}};

#pragma unroll 1
    for (int ch = 0; ch < 4; ++ch) {
        f16x8 a_h[CHK];
#pragma unroll
        for (int q = 0; q < CHK; ++q) {
            const int kk = ch * CHK + q;
            const int h0 = kk * 32 + lgrp * 8;
            float v[8];
            if (kk < NKK2 && h0 + 7 < PP * HH) {
                f32x4 p0 = *reinterpret_cast<const f32x4*>(arow + h0);
                f32x4 p1 = *reinterpret_cast<const f32x4*>(arow + h0 + 4);
                v[0] = p0[0]; v[1] = p0[1]; v[2] = p0[2]; v[3] = p0[3];
                v[4] = p1[0]; v[5] = p1[1]; v[6] = p1[2]; v[7] = p1[3];
            } else {
#pragma unroll
                for (int j = 0; j < 8; ++j)
                    v[j] = (kk < NKK2 && h0 + j < PP * HH) ? arow[h0 + j] : 0.f;
            }
#pragma unroll
            for (int j = 0; j < 8; ++j) {
                const int h = h0 + j;
                const int p = (h < PP * HH) ? (h / HH) : 0;
                a_h[q][j] = (_Float16)(v[j] * sm[p]);
            }
        }
#pragma unroll
        for (int q = 0; q < CHK; ++q) {
            const int kk = ch * CHK + q;
            if (kk < NKK2) {
#pragma unroll
                for (int c = 0; c < 5; ++c) {
                    const int ct = wv + 4 * c;
                    if (ct < NCT) {
                        f16x8 bh = WH[(kk * NCT + ct) * 64 + lane];
                        acc[c] = __builtin_amdgcn_mfma_f32_16x16x32_f16(a_h[q], bh, acc[c], 0, 0, 0);
                    }
                }
            }
        }
    }

    float rs0 = 0.f, rs1 = 0.f, rs2 = 0.f, rs3 = 0.f;
#pragma unroll
    for (int c = 0; c < 5; ++c) {
        const int ct = wv + 4 * c;
        if (ct < NCT) {
            const int k  = ct * 16 + lrow;
            const bool ok = k < HH;
            const int kc = ok ? k : (HH - 1);
            const float iv  = instr[b * HH + kc];
            const float wsv = ok ? w_state[kc] : 0.f;
            rs0 += eluf(acc[c][0] * iv) * wsv;
            rs1 += eluf(acc[c][1] * iv) * wsv;
            rs2 += eluf(acc[c][2] * iv) * wsv;
            rs3 += eluf(acc[c][3] * iv) * wsv;
        }
    }
#pragma unroll
    for (int msk = 1; msk < 16; msk <<= 1) {
        rs0 += __shfl_xor(rs0, msk);
        rs1 += __shfl_xor(rs1, msk);
        rs2 += __shfl_xor(rs2, msk);
        rs3 += __shfl_xor(rs3, msk);
    }
    if (lrow == 0) {
        red[wv][lgrp * 4 + 0] = rs0;
        red[wv][lgrp * 4 + 1] = rs1;
        red[wv][lgrp * 4 + 2] = rs2;
        red[wv][lgrp * 4 + 3] = rs3;
    }
    __syncthreads();
    if (tid < 16) {
        const int n = nt * 16 + tid;
        float v = red[0][tid] + red[1][tid] + red[2][tid] + red[3][tid];
        state_logits[b * NN + n] = v + node_mask[b * NN + n];
    }
}

// ---------------------------------------------------------------------------
// Fallback fp32 node path (used only if ws_size can't hold W_np fragments).
// ---------------------------------------------------------------------------
extern "C" __global__ __launch_bounds__(256)
void node_kernel(const float* __restrict__ node_attr,
                 const float* __restrict__ instr,
                 const float* __restrict__ sim,
                 const float* __restrict__ node_mask,
                 const float* __restrict__ w_np,
                 const float* __restrict__ w_state,
                 float* __restrict__ state_logits)
{
    __shared__ float As[8 * 1200];
    const int b   = (int)blockIdx.x >> 3;
    const int n0  = ((int)blockIdx.x & 7) * 8;
    const int tid = (int)threadIdx.x;
    const int tx  = tid & 31;
    const int r   = tid >> 5;

    {
        const float4* src = reinterpret_cast<const float4*>(
            node_attr + (size_t)(b * NN + n0) * (PP * HH));
        float4* dst = reinterpret_cast<float4*>(As);
#pragma unroll 1
        for (int i = tid; i < 8 * 1200 / 4; i += 256) {
            float4 v = src[i];
            int p = (i % 300) / 75;
            float s = sim[b * PP + p];
            v.x *= s; v.y *= s; v.z *= s; v.w *= s;
            dst[i] = v;
        }
    }
    __syncthreads();

    float spart = 0.f;
    const float4* A4 = reinterpret_cast<const float4*>(As) + r * 300;

#pragma unroll 1
    for (int ct = 0; ct < 3; ++ct) {
        int k0 = ct * 128 + (tx << 2);
        if (k0 + 3 >= HH) continue;
        float acc0 = 0.f, acc1 = 0.f, acc2 = 0.f, acc3 = 0.f;
#pragma unroll 2
        for (int hq = 0; hq < 300; ++hq) {
            float4 a = A4[hq];
            const float* wb = w_np + (size_t)(hq * 4) * HH + k0;
            float4 w0 = *reinterpret_cast<const float4*>(wb);
            float4 w1 = *reinterpret_cast<const float4*>(wb + HH);
            float4 w2 = *reinterpret_cast<const float4*>(wb + 2 * HH);
            float4 w3 = *reinterpret_cast<const float4*>(wb + 3 * HH);
            acc0 = fmaf(a.x, w0.x, fmaf(a.y, w1.x, fmaf(a.z, w2.x, fmaf(a.w, w3.x, acc0))));
            acc1 = fmaf(a.x, w0.y, fmaf(a.y, w1.y, fmaf(a.z, w2.y, fmaf(a.w, w3.y, acc1))));
            acc2 = fmaf(a.x, w0.z, fmaf(a.y, w1.z, fmaf(a.z, w2.z, fmaf(a.w, w3.z, acc2))));
            acc3 = fmaf(a.x, w0.w, fmaf(a.y, w1.w, fmaf(a.z, w2.w, fmaf(a.w, w3.w, acc3))));
        }
        float4 iv  = *reinterpret_cast<const float4*>(instr + b * HH + k0);
        float4 wsv = *reinterpret_cast<const float4*>(w_state + k0);
        spart += eluf(acc0 * iv.x) * wsv.x + eluf(acc1 * iv.y) * wsv.y +
                 eluf(acc2 * iv.z) * wsv.z + eluf(acc3 * iv.w) * wsv.w;
    }

#pragma unroll
    for (int msk = 1; msk < 32; msk <<= 1) spart += __shfl_xor(spart, msk);
    if (tx == 0)
        state_logits[b * NN + n0 + r] = spart + node_mask[b * NN + n0 + r];
}

// ---------------------------------------------------------------------------
// Final: softmax both logit sets over n (one wave per b) and blend.
// ---------------------------------------------------------------------------
extern "C" __global__ __launch_bounds__(64)
void final_kernel(const float* __restrict__ rel_logits,
                  const float* __restrict__ state_logits,
                  const float* __restrict__ rel_sim,
                  float* __restrict__ out)
{
    const int b = (int)blockIdx.x;
    const int n = (int)threadIdx.x;
    float sl = state_logits[b * NN + n];
    float rl = rel_logits[b * NN + n];

    float ms = sl, mr = rl;
#pragma unroll
    for (int msk = 1; msk < 64; msk <<= 1) {
        ms = fmaxf(ms, __shfl_xor(ms, msk));
        mr = fmaxf(mr, __shfl_xor(mr, msk));
    }
    float es = __expf(sl - ms);
    float er = __expf(rl - mr);
    float ss = es, sr = er;
#pragma unroll
    for (int msk = 1; msk < 64; msk <<= 1) {
        ss += __shfl_xor(ss, msk);
        sr += __shfl_xor(sr, msk);
    }
    float rr = rel_sim[b];
    out[b * NN + n] = rr * (er / sr) + (1.f - rr) * (es / ss);
}

extern "C" void kernel_launch(void* const* d_in, const int* in_sizes, int n_in,
                              void* d_out, int out_size, void* d_ws, size_t ws_size,
                              hipStream_t stream) {
    const float* node_attr    = (const float*)d_in[0];
    const float* edge_attr    = (const float*)d_in[1];
    const float* instruction  = (const float*)d_in[2];
    const float* distribution = (const float*)d_in[3];
    const float* node_sim     = (const float*)d_in[4];
    const float* rel_sim      = (const float*)d_in[5];
    const float* node_mask    = (const float*)d_in[6];
    const float* w_np         = (const float*)d_in[7];
    const float* w_edge       = (const float*)d_in[8];
    const float* w_state      = (const float*)d_in[9];
    const float* w_rel        = (const float*)d_in[10];
    float* out = (float*)d_out;

    // workspace layout
    float* rel_ws   = (float*)d_ws;                           // [2048] f32
    float* state_ws = rel_ws + BB * NN;                       // [2048] f32
    char*  wsb      = (char*)d_ws;
    const size_t edge_frag = (size_t)NKK * NCTE * 64 * 8 * 2;  // 204,800 B
    const size_t node_frag = (size_t)NKK2 * NCT * 64 * 8 * 2;  // 739,328 B
    _Float16* w_hi  = (_Float16*)(wsb + 16384);
    _Float16* w2_hi = (_Float16*)(wsb + 16384 + edge_frag);
    const size_t need = 16384 + edge_frag + node_frag;
    const bool node_mfma_ok = (ws_size >= need);

    wprep_kernel<<<dim3(NKK * NCTE), dim3(64), 0, stream>>>(w_edge, w_hi);

    edge_kernel<<<dim3(BB * NN / 2), dim3(512), 0, stream>>>(
        edge_attr, instruction, distribution, node_mask, w_hi, w_rel, rel_ws);

    if (node_mfma_ok) {
        wprep2_kernel<<<dim3(NKK2 * NCT), dim3(64), 0, stream>>>(w_np, w2_hi);
        node_mfma_kernel<<<dim3(BB * 4), dim3(256), 0, stream>>>(
            node_attr, instruction, node_sim, node_mask, w2_hi,
            w_state, state_ws);
    } else {
        node_kernel<<<dim3(BB * 8), dim3(256), 0, stream>>>(
            node_attr, instruction, node_sim, node_mask, w_np, w_state, state_ws);
    }

    final_kernel<<<dim3(BB), dim3(64), 0, stream>>>(
        rel_ws, state_ws, rel_sim, out);
}